// Round 1
// baseline (594.639 us; speedup 1.0000x reference)
//
#include <hip/hip_runtime.h>
#include <math.h>

typedef __bf16 bf16x8 __attribute__((ext_vector_type(8)));
typedef float f32x4 __attribute__((ext_vector_type(4)));

#define EPSV 1e-5f

__device__ __forceinline__ unsigned fkey(float f) {
  unsigned b = __float_as_uint(f);
  return (b & 0x80000000u) ? ~b : (b | 0x80000000u);
}
__device__ __forceinline__ float funkey(unsigned k) {
  return __uint_as_float((k & 0x80000000u) ? (k & 0x7fffffffu) : ~k);
}

// Per-pixel channel normalization: subtract target channel-mean from both gen
// and tar, L2-normalize over channels, store bf16 in [N][Ppad][C] (c-contiguous,
// i.e. K-contiguous for the MFMA fragments).
__global__ void norm_kernel(const float* __restrict__ gen, const float* __restrict__ tar,
                            __bf16* __restrict__ Ghat, __bf16* __restrict__ That,
                            int C, int P, int Ppad)
{
  int n = blockIdx.y;
  int p = blockIdx.x * blockDim.x + threadIdx.x;
  if (p >= Ppad) return;
  __bf16* tp = That + ((size_t)n * Ppad + p) * C;
  __bf16* gp = Ghat + ((size_t)n * Ppad + p) * C;
  if (p >= P) {  // zero padding rows
    bf16x8 z;
    for (int j = 0; j < 8; j++) z[j] = (__bf16)0.f;
    for (int c = 0; c < C; c += 8) {
      *(bf16x8*)(tp + c) = z;
      *(bf16x8*)(gp + c) = z;
    }
    return;
  }
  const float* tb = tar + (size_t)n * C * P + p;
  const float* gb = gen + (size_t)n * C * P + p;
  float st = 0.f, sst = 0.f, sg = 0.f, ssg = 0.f;
  for (int c = 0; c < C; c++) {
    float t = tb[(size_t)c * P];
    float g = gb[(size_t)c * P];
    st += t; sst += t * t; sg += g; ssg += g * g;
  }
  float m = st / (float)C;
  float vt = sst - st * st / (float)C;            // sum (t-m)^2
  float vg = ssg - 2.f * m * sg + (float)C * m * m; // sum (g-m)^2
  float it = rsqrtf(fmaxf(vt, 1e-30f));
  float ig = rsqrtf(fmaxf(vg, 1e-30f));
  for (int c0 = 0; c0 < C; c0 += 8) {
    bf16x8 tv, gv;
    for (int j = 0; j < 8; j++) {
      int c = c0 + j;
      tv[j] = (__bf16)((tb[(size_t)c * P] - m) * it);
      gv[j] = (__bf16)((gb[(size_t)c * P] - m) * ig);
    }
    *(bf16x8*)(tp + c0) = tv;
    *(bf16x8*)(gp + c0) = gv;
  }
}

// S[p][q] = sum_c That[p][c] * Ghat[q][c].  64x64 tile, 4 waves each doing a
// 32x32 quadrant with 2x2 mfma_f32_16x16x32_bf16.  Epilogue stores S (fp32)
// and atomicMax's the per-column max (for div[q]) via monotone uint keys.
__global__ __launch_bounds__(256) void gemm_kernel(
    const __bf16* __restrict__ That, const __bf16* __restrict__ Ghat,
    float* __restrict__ S, unsigned* __restrict__ divkey,
    int C, int Ppad, int Qpad, int Preal)
{
  __shared__ __attribute__((aligned(16))) __bf16 As[64][40];  // +8 pad: frag reads 2-way (free)
  __shared__ __attribute__((aligned(16))) __bf16 Bs[64][40];
  int n = blockIdx.z;
  int p0 = blockIdx.y * 64;
  int q0 = blockIdx.x * 64;
  int tid = threadIdx.x;
  int r = tid >> 2;            // staging row 0..63
  int kc = (tid & 3) * 8;      // staging k-chunk
  const __bf16* Aptr = That + ((size_t)n * Ppad + p0 + r) * C + kc;
  const __bf16* Bptr = Ghat + ((size_t)n * Qpad + q0 + r) * C + kc;

  int w = tid >> 6, lane = tid & 63;
  int wrow = (w >> 1) * 32, wcol = (w & 1) * 32;
  int lm = lane & 15, lq = lane >> 4;

  f32x4 zero = {0.f, 0.f, 0.f, 0.f};
  f32x4 acc[2][2] = {{zero, zero}, {zero, zero}};

  for (int c0 = 0; c0 < C; c0 += 32) {
    bf16x8 av = *(const bf16x8*)(Aptr + c0);
    bf16x8 bv = *(const bf16x8*)(Bptr + c0);
    __syncthreads();
    *(bf16x8*)&As[r][kc] = av;
    *(bf16x8*)&Bs[r][kc] = bv;
    __syncthreads();
    // A[m][k]: lane holds m=lm, k=lq*8+j ; B[k][n]: n=lm, k=lq*8+j
    bf16x8 a0 = *(const bf16x8*)&As[wrow + lm][lq * 8];
    bf16x8 a1 = *(const bf16x8*)&As[wrow + 16 + lm][lq * 8];
    bf16x8 b0 = *(const bf16x8*)&Bs[wcol + lm][lq * 8];
    bf16x8 b1 = *(const bf16x8*)&Bs[wcol + 16 + lm][lq * 8];
    acc[0][0] = __builtin_amdgcn_mfma_f32_16x16x32_bf16(a0, b0, acc[0][0], 0, 0, 0);
    acc[0][1] = __builtin_amdgcn_mfma_f32_16x16x32_bf16(a0, b1, acc[0][1], 0, 0, 0);
    acc[1][0] = __builtin_amdgcn_mfma_f32_16x16x32_bf16(a1, b0, acc[1][0], 0, 0, 0);
    acc[1][1] = __builtin_amdgcn_mfma_f32_16x16x32_bf16(a1, b1, acc[1][1], 0, 0, 0);
  }

  // D layout: row = lq*4 + reg, col = lm (within each 16x16 sub-tile)
  float* Sbase = S + (size_t)n * Ppad * Qpad;
  float colmax[2] = {-INFINITY, -INFINITY};
  for (int rt = 0; rt < 2; rt++) {
    for (int ct = 0; ct < 2; ct++) {
      for (int ri = 0; ri < 4; ri++) {
        int prow = p0 + wrow + rt * 16 + lq * 4 + ri;
        int qcol = q0 + wcol + ct * 16 + lm;
        float v = acc[rt][ct][ri];
        Sbase[(size_t)prow * Qpad + qcol] = v;
        if (prow < Preal) colmax[ct] = fmaxf(colmax[ct], v);  // mask padded rows
      }
    }
  }
  for (int ct = 0; ct < 2; ct++) {
    float v = colmax[ct];
    v = fmaxf(v, __shfl_xor(v, 16, 64));
    v = fmaxf(v, __shfl_xor(v, 32, 64));
    if (lq == 0 && v > -INFINITY) {
      int qcol = q0 + wcol + ct * 16 + lm;
      atomicMax(&divkey[(size_t)n * Qpad + qcol], fkey(v));
    }
  }
}

// invd[q] = 1 / (0.5*(1 - maxS[q]) + eps)
__global__ void invd_kernel(const unsigned* __restrict__ divkey, float* __restrict__ invd,
                            int Qreal, int Qpad)
{
  int n = blockIdx.y;
  int q = blockIdx.x * 256 + threadIdx.x;
  if (q >= Qreal) return;
  float maxS = funkey(divkey[(size_t)n * Qpad + q]);
  float d = 0.5f * (1.f - maxS) + EPSV;
  invd[(size_t)n * Qpad + q] = 1.f / d;
}

__global__ void recip_kernel(const float* __restrict__ Z, float* __restrict__ zinv,
                             int Qreal, int Qpad)
{
  int n = blockIdx.y;
  int q = blockIdx.x * 256 + threadIdx.x;
  if (q >= Qreal) return;
  zinv[(size_t)n * Qpad + q] = 1.f / Z[(size_t)n * Qpad + q];
}

// Z[q] = sum_p exp((S[p][q]-1) * invd[q])   (exp(2) constant cancels in cs)
__global__ __launch_bounds__(256) void z_kernel(
    const float* __restrict__ S, const float* __restrict__ invd,
    float* __restrict__ Z, int Preal, int Ppad, int Qreal, int Qpad, int rows_per_chunk)
{
  int n = blockIdx.z;
  int q4 = blockIdx.x * 256 + threadIdx.x;
  int q = q4 * 4;
  if (q >= Qreal) return;
  int pstart = blockIdx.y * rows_per_chunk;
  int pend = min(pstart + rows_per_chunk, Preal);
  f32x4 id = *(const f32x4*)(invd + (size_t)n * Qpad + q);
  const float* Sp = S + (size_t)n * Ppad * Qpad + q;
  f32x4 acc = {0.f, 0.f, 0.f, 0.f};
  for (int p = pstart; p < pend; p++) {
    f32x4 sv = *(const f32x4*)(Sp + (size_t)p * Qpad);
    for (int j = 0; j < 4; j++) acc[j] += __expf((sv[j] - 1.f) * id[j]);
  }
  float* zp = Z + (size_t)n * Qpad + q;
  for (int j = 0; j < 4; j++) atomicAdd(zp + j, acc[j]);
}

// kmax[p] = max_q exp((S[p][q]-1)*invd[q]) * zinv[q]
__global__ __launch_bounds__(256) void rowmax_kernel(
    const float* __restrict__ S, const float* __restrict__ invd,
    const float* __restrict__ zinv, float* __restrict__ kmax,
    int Qreal, int Qpad, int Ppad)
{
  int n = blockIdx.y;
  int p = blockIdx.x;
  const float* Sp = S + ((size_t)n * Ppad + p) * Qpad;
  const float* id = invd + (size_t)n * Qpad;
  const float* zi = zinv + (size_t)n * Qpad;
  int nq4 = Qreal >> 2;
  float m = 0.f;
  for (int i = threadIdx.x; i < nq4; i += 256) {
    f32x4 sv = *(const f32x4*)(Sp + (size_t)i * 4);
    f32x4 iv = *(const f32x4*)(id + (size_t)i * 4);
    f32x4 zv = *(const f32x4*)(zi + (size_t)i * 4);
    for (int j = 0; j < 4; j++)
      m = fmaxf(m, __expf((sv[j] - 1.f) * iv[j]) * zv[j]);
  }
  for (int off = 32; off > 0; off >>= 1)
    m = fmaxf(m, __shfl_xor(m, off, 64));
  __shared__ float red[4];
  if ((threadIdx.x & 63) == 0) red[threadIdx.x >> 6] = m;
  __syncthreads();
  if (threadIdx.x == 0) {
    m = fmaxf(fmaxf(red[0], red[1]), fmaxf(red[2], red[3]));
    kmax[(size_t)n * Ppad + p] = m;
  }
}

// loss = 0.5 * sum_n -log(mean_p kmax3) + 1.0 * sum_n -log(mean_p kmax4)
__global__ void final_kernel(const float* __restrict__ kmax3, const float* __restrict__ kmax4,
                             float* __restrict__ out)
{
  __shared__ float red[256];
  int tid = threadIdx.x;
  float total = 0.f;
  for (int l = 0; l < 2; l++) {
    const float* km = l ? kmax4 : kmax3;
    int P = l ? 784 : 3136;
    int Ppad = l ? 832 : 3136;
    float wgt = l ? 1.0f : 0.5f;
    for (int n = 0; n < 4; n++) {
      float s = 0.f;
      for (int i = tid; i < P; i += 256) s += km[(size_t)n * Ppad + i];
      red[tid] = s;
      __syncthreads();
      for (int st = 128; st > 0; st >>= 1) {
        if (tid < st) red[tid] += red[tid + st];
        __syncthreads();
      }
      if (tid == 0) total += wgt * (-logf(red[0] / (float)P));
      __syncthreads();
    }
  }
  if (tid == 0) out[0] = total;
}

extern "C" void kernel_launch(void* const* d_in, const int* in_sizes, int n_in,
                              void* d_out, int out_size, void* d_ws, size_t ws_size,
                              hipStream_t stream)
{
  const float* gen3 = (const float*)d_in[0];
  const float* tar3 = (const float*)d_in[1];
  const float* gen4 = (const float*)d_in[2];
  const float* tar4 = (const float*)d_in[3];

  // Layer3: N=4, C=256, P=Q=3136 (=49*64, no pad). Layer4: N=4, C=512, P=Q=784, pad 832.
  char* ws = (char*)d_ws;
  size_t off = 0;
  auto take = [&](size_t bytes) { char* p = ws + off; off += bytes; return p; };

  __bf16* That3 = (__bf16*)take(6422528);      // 4*3136*256*2
  __bf16* Ghat3 = (__bf16*)take(6422528);
  __bf16* That4 = (__bf16*)take(3407872);      // 4*832*512*2
  __bf16* Ghat4 = (__bf16*)take(3407872);
  float*  S3    = (float*) take(157351936);    // 4*3136*3136*4
  float*  S4    = (float*) take(11075584);     // 4*832*832*4
  unsigned* divkey3 = (unsigned*)take(50176);  // 4*3136*4
  float*  Z3    = (float*) take(50176);
  unsigned* divkey4 = (unsigned*)take(13312);  // 4*832*4
  float*  Z4    = (float*) take(13312);
  float* invd3  = (float*)take(50176);
  float* zinv3  = (float*)take(50176);
  float* kmax3  = (float*)take(50176);
  float* invd4  = (float*)take(13312);
  float* zinv4  = (float*)take(13312);
  float* kmax4  = (float*)take(13312);

  // zero divkey3, Z3, divkey4, Z4 (contiguous)
  hipMemsetAsync(divkey3, 0, 50176 + 50176 + 13312 + 13312, stream);

  norm_kernel<<<dim3(13, 4), 256, 0, stream>>>(gen3, tar3, Ghat3, That3, 256, 3136, 3136);
  norm_kernel<<<dim3(4, 4), 256, 0, stream>>>(gen4, tar4, Ghat4, That4, 512, 784, 832);

  gemm_kernel<<<dim3(49, 49, 4), 256, 0, stream>>>(That3, Ghat3, S3, divkey3, 256, 3136, 3136, 3136);
  gemm_kernel<<<dim3(13, 13, 4), 256, 0, stream>>>(That4, Ghat4, S4, divkey4, 512, 832, 832, 784);

  invd_kernel<<<dim3(13, 4), 256, 0, stream>>>(divkey3, invd3, 3136, 3136);
  invd_kernel<<<dim3(4, 4), 256, 0, stream>>>(divkey4, invd4, 784, 832);

  z_kernel<<<dim3(4, 32, 4), 256, 0, stream>>>(S3, invd3, Z3, 3136, 3136, 3136, 3136, 98);
  z_kernel<<<dim3(1, 16, 4), 256, 0, stream>>>(S4, invd4, Z4, 784, 832, 784, 832, 49);

  recip_kernel<<<dim3(13, 4), 256, 0, stream>>>(Z3, zinv3, 3136, 3136);
  recip_kernel<<<dim3(4, 4), 256, 0, stream>>>(Z4, zinv4, 784, 832);

  rowmax_kernel<<<dim3(3136, 4), 256, 0, stream>>>(S3, invd3, zinv3, kmax3, 3136, 3136, 3136);
  rowmax_kernel<<<dim3(784, 4), 256, 0, stream>>>(S4, invd4, zinv4, kmax4, 784, 832, 832);

  final_kernel<<<1, 256, 0, stream>>>(kmax3, kmax4, (float*)d_out);
}

// Round 2
// 302.005 us; speedup vs baseline: 1.9690x; 1.9690x over previous
//
#include <hip/hip_runtime.h>
#include <math.h>

typedef __bf16 bf16x8 __attribute__((ext_vector_type(8)));
typedef float f32x4 __attribute__((ext_vector_type(4)));

#define EPSV 1e-5f

__device__ __forceinline__ unsigned fkey(float f) {
  unsigned b = __float_as_uint(f);
  return (b & 0x80000000u) ? ~b : (b | 0x80000000u);
}
__device__ __forceinline__ float funkey(unsigned k) {
  return __uint_as_float((k & 0x80000000u) ? (k & 0x7fffffffu) : ~k);
}

// Pass 1 of normalization: per-pixel sums (st, sst, sg, ssg) accumulated into
// acc[n][p] via atomics. Grid (ceil(P/64), C/32, N); each thread sums 8
// channels for one pixel; lanes are p-consecutive -> coalesced loads.
__global__ __launch_bounds__(256) void stats_kernel(
    const float* __restrict__ gen, const float* __restrict__ tar,
    float* __restrict__ acc, int C, int P, int Ppad)
{
  int n = blockIdx.z;
  int pl = threadIdx.x & 63, g = threadIdx.x >> 6;
  int p = blockIdx.x * 64 + pl;
  int c0 = blockIdx.y * 32 + g * 8;
  float st = 0.f, sst = 0.f, sg = 0.f, ssg = 0.f;
  if (p < P) {
    const float* tb = tar + (size_t)n * C * P + (size_t)c0 * P + p;
    const float* gb = gen + (size_t)n * C * P + (size_t)c0 * P + p;
    for (int j = 0; j < 8; j++) {
      float t = tb[(size_t)j * P];
      float gv = gb[(size_t)j * P];
      st += t; sst += t * t; sg += gv; ssg += gv * gv;
    }
  }
  __shared__ f32x4 red[4][64];
  red[g][pl] = f32x4{st, sst, sg, ssg};
  __syncthreads();
  if (g == 0 && p < P) {
    for (int k = 1; k < 4; k++) {
      f32x4 r = red[k][pl];
      st += r[0]; sst += r[1]; sg += r[2]; ssg += r[3];
    }
    float* a = acc + ((size_t)n * Ppad + p) * 4;
    atomicAdd(a + 0, st);
    atomicAdd(a + 1, sst);
    atomicAdd(a + 2, sg);
    atomicAdd(a + 3, ssg);
  }
}

// Pass 2: read per-pixel sums, normalize, write bf16 [N][Ppad][C] (C-contig).
// Grid (ceil(Ppad/256), C/8, N).
__global__ __launch_bounds__(256) void apply_kernel(
    const float* __restrict__ gen, const float* __restrict__ tar,
    const float* __restrict__ acc,
    __bf16* __restrict__ Ghat, __bf16* __restrict__ That,
    int C, int P, int Ppad)
{
  int n = blockIdx.z;
  int p = blockIdx.x * 256 + threadIdx.x;
  int c0 = blockIdx.y * 8;
  if (p >= Ppad) return;
  __bf16* tp = That + ((size_t)n * Ppad + p) * C + c0;
  __bf16* gp = Ghat + ((size_t)n * Ppad + p) * C + c0;
  if (p >= P) {
    bf16x8 z;
    for (int j = 0; j < 8; j++) z[j] = (__bf16)0.f;
    *(bf16x8*)tp = z;
    *(bf16x8*)gp = z;
    return;
  }
  const float* a = acc + ((size_t)n * Ppad + p) * 4;
  float st = a[0], sst = a[1], sg = a[2], ssg = a[3];
  float m = st / (float)C;
  float vt = sst - st * st / (float)C;
  float vg = ssg - 2.f * m * sg + (float)C * m * m;
  float it = rsqrtf(fmaxf(vt, 1e-30f));
  float ig = rsqrtf(fmaxf(vg, 1e-30f));
  const float* tb = tar + (size_t)n * C * P + (size_t)c0 * P + p;
  const float* gb = gen + (size_t)n * C * P + (size_t)c0 * P + p;
  bf16x8 tv, gv;
  for (int j = 0; j < 8; j++) {
    tv[j] = (__bf16)((tb[(size_t)j * P] - m) * it);
    gv[j] = (__bf16)((gb[(size_t)j * P] - m) * ig);
  }
  *(bf16x8*)tp = tv;
  *(bf16x8*)gp = gv;
}

// S[p][q] = sum_c That[p][c] * Ghat[q][c].  64x64 tile, 4 waves each doing a
// 32x32 quadrant with 2x2 mfma_f32_16x16x32_bf16.  Epilogue stores S (fp32)
// and atomicMax's the per-column max (for div[q]) via monotone uint keys.
__global__ __launch_bounds__(256) void gemm_kernel(
    const __bf16* __restrict__ That, const __bf16* __restrict__ Ghat,
    float* __restrict__ S, unsigned* __restrict__ divkey,
    int C, int Ppad, int Qpad, int Preal)
{
  __shared__ __attribute__((aligned(16))) __bf16 As[64][40];
  __shared__ __attribute__((aligned(16))) __bf16 Bs[64][40];
  int n = blockIdx.z;
  int p0 = blockIdx.y * 64;
  int q0 = blockIdx.x * 64;
  int tid = threadIdx.x;
  int r = tid >> 2;
  int kc = (tid & 3) * 8;
  const __bf16* Aptr = That + ((size_t)n * Ppad + p0 + r) * C + kc;
  const __bf16* Bptr = Ghat + ((size_t)n * Qpad + q0 + r) * C + kc;

  int w = tid >> 6, lane = tid & 63;
  int wrow = (w >> 1) * 32, wcol = (w & 1) * 32;
  int lm = lane & 15, lq = lane >> 4;

  f32x4 zero = {0.f, 0.f, 0.f, 0.f};
  f32x4 acc[2][2] = {{zero, zero}, {zero, zero}};

  for (int c0 = 0; c0 < C; c0 += 32) {
    bf16x8 av = *(const bf16x8*)(Aptr + c0);
    bf16x8 bv = *(const bf16x8*)(Bptr + c0);
    __syncthreads();
    *(bf16x8*)&As[r][kc] = av;
    *(bf16x8*)&Bs[r][kc] = bv;
    __syncthreads();
    bf16x8 a0 = *(const bf16x8*)&As[wrow + lm][lq * 8];
    bf16x8 a1 = *(const bf16x8*)&As[wrow + 16 + lm][lq * 8];
    bf16x8 b0 = *(const bf16x8*)&Bs[wcol + lm][lq * 8];
    bf16x8 b1 = *(const bf16x8*)&Bs[wcol + 16 + lm][lq * 8];
    acc[0][0] = __builtin_amdgcn_mfma_f32_16x16x32_bf16(a0, b0, acc[0][0], 0, 0, 0);
    acc[0][1] = __builtin_amdgcn_mfma_f32_16x16x32_bf16(a0, b1, acc[0][1], 0, 0, 0);
    acc[1][0] = __builtin_amdgcn_mfma_f32_16x16x32_bf16(a1, b0, acc[1][0], 0, 0, 0);
    acc[1][1] = __builtin_amdgcn_mfma_f32_16x16x32_bf16(a1, b1, acc[1][1], 0, 0, 0);
  }

  float* Sbase = S + (size_t)n * Ppad * Qpad;
  float colmax[2] = {-INFINITY, -INFINITY};
  for (int rt = 0; rt < 2; rt++) {
    for (int ct = 0; ct < 2; ct++) {
      for (int ri = 0; ri < 4; ri++) {
        int prow = p0 + wrow + rt * 16 + lq * 4 + ri;
        int qcol = q0 + wcol + ct * 16 + lm;
        float v = acc[rt][ct][ri];
        Sbase[(size_t)prow * Qpad + qcol] = v;
        if (prow < Preal) colmax[ct] = fmaxf(colmax[ct], v);
      }
    }
  }
  for (int ct = 0; ct < 2; ct++) {
    float v = colmax[ct];
    v = fmaxf(v, __shfl_xor(v, 16, 64));
    v = fmaxf(v, __shfl_xor(v, 32, 64));
    if (lq == 0 && v > -INFINITY) {
      int qcol = q0 + wcol + ct * 16 + lm;
      atomicMax(&divkey[(size_t)n * Qpad + qcol], fkey(v));
    }
  }
}

// invd[q] = 1 / (0.5*(1 - maxS[q]) + eps)
__global__ void invd_kernel(const unsigned* __restrict__ divkey, float* __restrict__ invd,
                            int Qreal, int Qpad)
{
  int n = blockIdx.y;
  int q = blockIdx.x * 256 + threadIdx.x;
  if (q >= Qreal) return;
  float maxS = funkey(divkey[(size_t)n * Qpad + q]);
  float d = 0.5f * (1.f - maxS) + EPSV;
  invd[(size_t)n * Qpad + q] = 1.f / d;
}

__global__ void recip_kernel(const float* __restrict__ Z, float* __restrict__ zinv,
                             int Qreal, int Qpad)
{
  int n = blockIdx.y;
  int q = blockIdx.x * 256 + threadIdx.x;
  if (q >= Qreal) return;
  zinv[(size_t)n * Qpad + q] = 1.f / Z[(size_t)n * Qpad + q];
}

// Z[q] = sum_p exp((S[p][q]-1) * invd[q])
__global__ __launch_bounds__(256) void z_kernel(
    const float* __restrict__ S, const float* __restrict__ invd,
    float* __restrict__ Z, int Preal, int Ppad, int Qreal, int Qpad, int rows_per_chunk)
{
  int n = blockIdx.z;
  int q4 = blockIdx.x * 256 + threadIdx.x;
  int q = q4 * 4;
  if (q >= Qreal) return;
  int pstart = blockIdx.y * rows_per_chunk;
  int pend = min(pstart + rows_per_chunk, Preal);
  f32x4 id = *(const f32x4*)(invd + (size_t)n * Qpad + q);
  const float* Sp = S + (size_t)n * Ppad * Qpad + q;
  f32x4 acc = {0.f, 0.f, 0.f, 0.f};
  for (int p = pstart; p < pend; p++) {
    f32x4 sv = *(const f32x4*)(Sp + (size_t)p * Qpad);
    for (int j = 0; j < 4; j++) acc[j] += __expf((sv[j] - 1.f) * id[j]);
  }
  float* zp = Z + (size_t)n * Qpad + q;
  for (int j = 0; j < 4; j++) atomicAdd(zp + j, acc[j]);
}

// kmax[p] = max_q exp((S[p][q]-1)*invd[q]) * zinv[q]
__global__ __launch_bounds__(256) void rowmax_kernel(
    const float* __restrict__ S, const float* __restrict__ invd,
    const float* __restrict__ zinv, float* __restrict__ kmax,
    int Qreal, int Qpad, int Ppad)
{
  int n = blockIdx.y;
  int p = blockIdx.x;
  const float* Sp = S + ((size_t)n * Ppad + p) * Qpad;
  const float* id = invd + (size_t)n * Qpad;
  const float* zi = zinv + (size_t)n * Qpad;
  int nq4 = Qreal >> 2;
  float m = 0.f;
  for (int i = threadIdx.x; i < nq4; i += 256) {
    f32x4 sv = *(const f32x4*)(Sp + (size_t)i * 4);
    f32x4 iv = *(const f32x4*)(id + (size_t)i * 4);
    f32x4 zv = *(const f32x4*)(zi + (size_t)i * 4);
    for (int j = 0; j < 4; j++)
      m = fmaxf(m, __expf((sv[j] - 1.f) * iv[j]) * zv[j]);
  }
  for (int off = 32; off > 0; off >>= 1)
    m = fmaxf(m, __shfl_xor(m, off, 64));
  __shared__ float red[4];
  if ((threadIdx.x & 63) == 0) red[threadIdx.x >> 6] = m;
  __syncthreads();
  if (threadIdx.x == 0) {
    m = fmaxf(fmaxf(red[0], red[1]), fmaxf(red[2], red[3]));
    kmax[(size_t)n * Ppad + p] = m;
  }
}

// loss = 0.5 * sum_n -log(mean_p kmax3) + 1.0 * sum_n -log(mean_p kmax4)
__global__ void final_kernel(const float* __restrict__ kmax3, const float* __restrict__ kmax4,
                             float* __restrict__ out)
{
  __shared__ float red[256];
  int tid = threadIdx.x;
  float total = 0.f;
  for (int l = 0; l < 2; l++) {
    const float* km = l ? kmax4 : kmax3;
    int P = l ? 784 : 3136;
    int Ppad = l ? 832 : 3136;
    float wgt = l ? 1.0f : 0.5f;
    for (int n = 0; n < 4; n++) {
      float s = 0.f;
      for (int i = tid; i < P; i += 256) s += km[(size_t)n * Ppad + i];
      red[tid] = s;
      __syncthreads();
      for (int st = 128; st > 0; st >>= 1) {
        if (tid < st) red[tid] += red[tid + st];
        __syncthreads();
      }
      if (tid == 0) total += wgt * (-logf(red[0] / (float)P));
      __syncthreads();
    }
  }
  if (tid == 0) out[0] = total;
}

extern "C" void kernel_launch(void* const* d_in, const int* in_sizes, int n_in,
                              void* d_out, int out_size, void* d_ws, size_t ws_size,
                              hipStream_t stream)
{
  const float* gen3 = (const float*)d_in[0];
  const float* tar3 = (const float*)d_in[1];
  const float* gen4 = (const float*)d_in[2];
  const float* tar4 = (const float*)d_in[3];

  // Layer3: N=4, C=256, P=Q=3136 (=49*64, no pad). Layer4: N=4, C=512, P=784, pad 832.
  char* ws = (char*)d_ws;
  size_t off = 0;
  auto take = [&](size_t bytes) { char* p = ws + off; off += bytes; return p; };

  // ---- zeroed region (one contiguous memset) ----
  unsigned* divkey3 = (unsigned*)take(50176);  // 4*3136*4
  float*  Z3    = (float*) take(50176);
  unsigned* divkey4 = (unsigned*)take(13312);  // 4*832*4
  float*  Z4    = (float*) take(13312);
  float*  acc3  = (float*) take(200704);       // 4*3136*4*4
  float*  acc4  = (float*) take(53248);        // 4*832*4*4
  size_t zero_bytes = off;
  // ---- rest ----
  __bf16* That3 = (__bf16*)take(6422528);      // 4*3136*256*2
  __bf16* Ghat3 = (__bf16*)take(6422528);
  __bf16* That4 = (__bf16*)take(3407872);      // 4*832*512*2
  __bf16* Ghat4 = (__bf16*)take(3407872);
  float*  S3    = (float*) take(157351936);    // 4*3136*3136*4
  float*  S4    = (float*) take(11075584);     // 4*832*832*4
  float* invd3  = (float*)take(50176);
  float* zinv3  = (float*)take(50176);
  float* kmax3  = (float*)take(50176);
  float* invd4  = (float*)take(13312);
  float* zinv4  = (float*)take(13312);
  float* kmax4  = (float*)take(13312);

  hipMemsetAsync(divkey3, 0, zero_bytes, stream);

  stats_kernel<<<dim3(49, 8, 4), 256, 0, stream>>>(gen3, tar3, acc3, 256, 3136, 3136);
  stats_kernel<<<dim3(13, 16, 4), 256, 0, stream>>>(gen4, tar4, acc4, 512, 784, 832);

  apply_kernel<<<dim3(13, 32, 4), 256, 0, stream>>>(gen3, tar3, acc3, Ghat3, That3, 256, 3136, 3136);
  apply_kernel<<<dim3(4, 64, 4), 256, 0, stream>>>(gen4, tar4, acc4, Ghat4, That4, 512, 784, 832);

  gemm_kernel<<<dim3(49, 49, 4), 256, 0, stream>>>(That3, Ghat3, S3, divkey3, 256, 3136, 3136, 3136);
  gemm_kernel<<<dim3(13, 13, 4), 256, 0, stream>>>(That4, Ghat4, S4, divkey4, 512, 832, 832, 784);

  invd_kernel<<<dim3(13, 4), 256, 0, stream>>>(divkey3, invd3, 3136, 3136);
  invd_kernel<<<dim3(4, 4), 256, 0, stream>>>(divkey4, invd4, 784, 832);

  z_kernel<<<dim3(4, 32, 4), 256, 0, stream>>>(S3, invd3, Z3, 3136, 3136, 3136, 3136, 98);
  z_kernel<<<dim3(1, 16, 4), 256, 0, stream>>>(S4, invd4, Z4, 784, 832, 784, 832, 49);

  recip_kernel<<<dim3(13, 4), 256, 0, stream>>>(Z3, zinv3, 3136, 3136);
  recip_kernel<<<dim3(4, 4), 256, 0, stream>>>(Z4, zinv4, 784, 832);

  rowmax_kernel<<<dim3(3136, 4), 256, 0, stream>>>(S3, invd3, zinv3, kmax3, 3136, 3136, 3136);
  rowmax_kernel<<<dim3(784, 4), 256, 0, stream>>>(S4, invd4, zinv4, kmax4, 784, 832, 832);

  final_kernel<<<1, 256, 0, stream>>>(kmax3, kmax4, (float*)d_out);
}

// Round 3
// 292.845 us; speedup vs baseline: 2.0306x; 1.0313x over previous
//
#include <hip/hip_runtime.h>
#include <math.h>

typedef __bf16 bf16x8 __attribute__((ext_vector_type(8)));
typedef float f32x4 __attribute__((ext_vector_type(4)));

#define EPSV 1e-5f

#define GLB(p) ((__attribute__((address_space(1))) void*)(p))
#define LDS(p) ((__attribute__((address_space(3))) void*)(p))

__device__ __forceinline__ unsigned fkey(float f) {
  unsigned b = __float_as_uint(f);
  return (b & 0x80000000u) ? ~b : (b | 0x80000000u);
}
__device__ __forceinline__ float funkey(unsigned k) {
  return __uint_as_float((k & 0x80000000u) ? (k & 0x7fffffffu) : ~k);
}

// Pass 1 of normalization: per-pixel sums (st, sst, sg, ssg) into acc via atomics.
__global__ __launch_bounds__(256) void stats_kernel(
    const float* __restrict__ gen, const float* __restrict__ tar,
    float* __restrict__ acc, int C, int P, int Ppad)
{
  int n = blockIdx.z;
  int pl = threadIdx.x & 63, g = threadIdx.x >> 6;
  int p = blockIdx.x * 64 + pl;
  int c0 = blockIdx.y * 32 + g * 8;
  float st = 0.f, sst = 0.f, sg = 0.f, ssg = 0.f;
  if (p < P) {
    const float* tb = tar + (size_t)n * C * P + (size_t)c0 * P + p;
    const float* gb = gen + (size_t)n * C * P + (size_t)c0 * P + p;
    for (int j = 0; j < 8; j++) {
      float t = tb[(size_t)j * P];
      float gv = gb[(size_t)j * P];
      st += t; sst += t * t; sg += gv; ssg += gv * gv;
    }
  }
  __shared__ f32x4 red[4][64];
  red[g][pl] = f32x4{st, sst, sg, ssg};
  __syncthreads();
  if (g == 0 && p < P) {
    for (int k = 1; k < 4; k++) {
      f32x4 r = red[k][pl];
      st += r[0]; sst += r[1]; sg += r[2]; ssg += r[3];
    }
    float* a = acc + ((size_t)n * Ppad + p) * 4;
    atomicAdd(a + 0, st);
    atomicAdd(a + 1, sst);
    atomicAdd(a + 2, sg);
    atomicAdd(a + 3, ssg);
  }
}

// Pass 2: normalize, write bf16 [N][Ppad][C] (C-contiguous), zero pad rows.
__global__ __launch_bounds__(256) void apply_kernel(
    const float* __restrict__ gen, const float* __restrict__ tar,
    const float* __restrict__ acc,
    __bf16* __restrict__ Ghat, __bf16* __restrict__ That,
    int C, int P, int Ppad)
{
  int n = blockIdx.z;
  int p = blockIdx.x * 256 + threadIdx.x;
  int c0 = blockIdx.y * 8;
  if (p >= Ppad) return;
  __bf16* tp = That + ((size_t)n * Ppad + p) * C + c0;
  __bf16* gp = Ghat + ((size_t)n * Ppad + p) * C + c0;
  if (p >= P) {
    bf16x8 z;
    for (int j = 0; j < 8; j++) z[j] = (__bf16)0.f;
    *(bf16x8*)tp = z;
    *(bf16x8*)gp = z;
    return;
  }
  const float* a = acc + ((size_t)n * Ppad + p) * 4;
  float st = a[0], sst = a[1], sg = a[2], ssg = a[3];
  float m = st / (float)C;
  float vt = sst - st * st / (float)C;
  float vg = ssg - 2.f * m * sg + (float)C * m * m;
  float it = rsqrtf(fmaxf(vt, 1e-30f));
  float ig = rsqrtf(fmaxf(vg, 1e-30f));
  const float* tb = tar + (size_t)n * C * P + (size_t)c0 * P + p;
  const float* gb = gen + (size_t)n * C * P + (size_t)c0 * P + p;
  bf16x8 tv, gv;
  for (int j = 0; j < 8; j++) {
    tv[j] = (__bf16)((tb[(size_t)j * P] - m) * it);
    gv[j] = (__bf16)((gb[(size_t)j * P] - m) * ig);
  }
  *(bf16x8*)tp = tv;
  *(bf16x8*)gp = gv;
}

// m97-structure GEMM: 128x128 tile, BK=32, 4 waves x (4x4) 16x16x32 mfma,
// global_load_lds width-16 staging.  S stored bf16; per-column max -> divkey.
__global__ __launch_bounds__(256) void gemm_kernel(
    const __bf16* __restrict__ A, const __bf16* __restrict__ B,
    __bf16* __restrict__ S, unsigned* __restrict__ divkey,
    int C, int Ppad, int Qpad, int Preal)
{
  __shared__ __attribute__((aligned(16))) __bf16 As[128 * 32];
  __shared__ __attribute__((aligned(16))) __bf16 Bs[128 * 32];
  int n = blockIdx.z;
  int p0 = blockIdx.y * 128, q0 = blockIdx.x * 128;
  int tid = threadIdx.x;
  int w = tid >> 6, lane = tid & 63;
  int lm = lane & 15, lq = lane >> 4;
  int wrow = (w >> 1) * 64, wcol = (w & 1) * 64;

  // staging: thread t covers row t/4 (and +64), k-chunk (t%3)*8, 16B each
  int srow = tid >> 2;
  int skc = (tid & 3) * 8;
  const __bf16* gA0 = A + ((size_t)n * Ppad + p0 + srow) * C + skc;
  const __bf16* gA1 = gA0 + (size_t)64 * C;
  const __bf16* gB0 = B + ((size_t)n * Qpad + q0 + srow) * C + skc;
  const __bf16* gB1 = gB0 + (size_t)64 * C;
  char* lA = (char*)As + w * 1024;  // wave-uniform: lane l lands at +l*16
  char* lB = (char*)Bs + w * 1024;

  f32x4 acc[4][4];
  for (int i = 0; i < 4; i++)
    for (int j = 0; j < 4; j++)
      acc[i][j] = f32x4{0.f, 0.f, 0.f, 0.f};

  for (int k0 = 0; k0 < C; k0 += 32) {
    __syncthreads();  // all waves done reading previous tile
    __builtin_amdgcn_global_load_lds(GLB(gA0 + k0), LDS(lA), 16, 0, 0);
    __builtin_amdgcn_global_load_lds(GLB(gA1 + k0), LDS(lA + 4096), 16, 0, 0);
    __builtin_amdgcn_global_load_lds(GLB(gB0 + k0), LDS(lB), 16, 0, 0);
    __builtin_amdgcn_global_load_lds(GLB(gB1 + k0), LDS(lB + 4096), 16, 0, 0);
    __syncthreads();  // vmcnt(0) drain: LDS tiles ready
    bf16x8 af[4], bf[4];
    for (int i = 0; i < 4; i++)
      af[i] = *(const bf16x8*)&As[(wrow + i * 16 + lm) * 32 + lq * 8];
    for (int j = 0; j < 4; j++)
      bf[j] = *(const bf16x8*)&Bs[(wcol + j * 16 + lm) * 32 + lq * 8];
    for (int i = 0; i < 4; i++)
      for (int j = 0; j < 4; j++)
        acc[i][j] = __builtin_amdgcn_mfma_f32_16x16x32_bf16(af[i], bf[j], acc[i][j], 0, 0, 0);
  }

  // Epilogue: D row = lq*4+ri, col = lm (within 16x16 sub-tile)
  __bf16* Sb = S + (size_t)n * Ppad * Qpad;
  float cm[4] = {-INFINITY, -INFINITY, -INFINITY, -INFINITY};
  for (int i = 0; i < 4; i++) {
    for (int j = 0; j < 4; j++) {
      for (int ri = 0; ri < 4; ri++) {
        int pr = p0 + wrow + i * 16 + lq * 4 + ri;
        int qc = q0 + wcol + j * 16 + lm;
        __bf16 bv = (__bf16)acc[i][j][ri];
        Sb[(size_t)pr * Qpad + qc] = bv;
        if (pr < Preal) cm[j] = fmaxf(cm[j], (float)bv);
      }
    }
  }
  for (int j = 0; j < 4; j++) {
    float v = cm[j];
    v = fmaxf(v, __shfl_xor(v, 16, 64));
    v = fmaxf(v, __shfl_xor(v, 32, 64));
    if (lq == 0 && v > -INFINITY) {
      int qc = q0 + wcol + j * 16 + lm;
      atomicMax(&divkey[(size_t)n * Qpad + qc], fkey(v));
    }
  }
}

// invd[q] = 1 / (0.5*(1 - maxS[q]) + eps)
__global__ void invd_kernel(const unsigned* __restrict__ divkey, float* __restrict__ invd,
                            int Qreal, int Qpad)
{
  int n = blockIdx.y;
  int q = blockIdx.x * 256 + threadIdx.x;
  if (q >= Qreal) return;
  float maxS = funkey(divkey[(size_t)n * Qpad + q]);
  float d = 0.5f * (1.f - maxS) + EPSV;
  invd[(size_t)n * Qpad + q] = 1.f / d;
}

// c[q] = -log(Z[q]) - invd[q]   (so  e*zinv = exp(S*invd + c))
__global__ void prep_kernel(const float* __restrict__ Z, const float* __restrict__ invd,
                            float* __restrict__ c, int Qreal, int Qpad)
{
  int n = blockIdx.y;
  int q = blockIdx.x * 256 + threadIdx.x;
  if (q >= Qreal) return;
  size_t idx = (size_t)n * Qpad + q;
  c[idx] = -logf(Z[idx]) - invd[idx];
}

// Z[q] = sum_p exp((S[p][q]-1) * invd[q]) ; S is bf16
__global__ __launch_bounds__(256) void z_kernel(
    const __bf16* __restrict__ S, const float* __restrict__ invd,
    float* __restrict__ Z, int Preal, int Ppad, int Qreal, int Qpad, int rows_per_chunk)
{
  int n = blockIdx.z;
  int q = (blockIdx.x * 256 + threadIdx.x) * 8;
  if (q >= Qreal) return;
  int p0 = blockIdx.y * rows_per_chunk;
  int p1 = min(p0 + rows_per_chunk, Preal);
  float id[8], nid[8];
  for (int j = 0; j < 8; j++) {
    id[j] = invd[(size_t)n * Qpad + q + j];
    nid[j] = -id[j];
  }
  const __bf16* Sp = S + (size_t)n * Ppad * Qpad + q;
  float acc[8] = {0.f, 0.f, 0.f, 0.f, 0.f, 0.f, 0.f, 0.f};
  for (int p = p0; p < p1; p++) {
    bf16x8 sv = *(const bf16x8*)(Sp + (size_t)p * Qpad);
    for (int j = 0; j < 8; j++)
      acc[j] += __expf(fmaf((float)sv[j], id[j], nid[j]));
  }
  float* zp = Z + (size_t)n * Qpad + q;
  for (int j = 0; j < 8; j++) atomicAdd(zp + j, acc[j]);
}

// kmax[p] = exp(max_q (S[p][q]*invd[q] + c[q])) ; 4 rows per block
__global__ __launch_bounds__(256) void rowmax_kernel(
    const __bf16* __restrict__ S, const float* __restrict__ invd,
    const float* __restrict__ c, float* __restrict__ kmax,
    int Qreal, int Qpad, int Ppad)
{
  int n = blockIdx.y;
  int p0 = blockIdx.x * 4;
  const __bf16* Sp = S + ((size_t)n * Ppad + p0) * Qpad;
  const float* id = invd + (size_t)n * Qpad;
  const float* cc = c + (size_t)n * Qpad;
  int nq8 = Qreal >> 3;
  float m[4] = {-INFINITY, -INFINITY, -INFINITY, -INFINITY};
  for (int i = threadIdx.x; i < nq8; i += 256) {
    f32x4 i0 = *(const f32x4*)(id + (size_t)i * 8);
    f32x4 i1 = *(const f32x4*)(id + (size_t)i * 8 + 4);
    f32x4 c0 = *(const f32x4*)(cc + (size_t)i * 8);
    f32x4 c1 = *(const f32x4*)(cc + (size_t)i * 8 + 4);
    for (int r = 0; r < 4; r++) {
      bf16x8 sv = *(const bf16x8*)(Sp + (size_t)r * Qpad + (size_t)i * 8);
      for (int j = 0; j < 4; j++)
        m[r] = fmaxf(m[r], fmaf((float)sv[j], i0[j], c0[j]));
      for (int j = 0; j < 4; j++)
        m[r] = fmaxf(m[r], fmaf((float)sv[j + 4], i1[j], c1[j]));
    }
  }
  for (int r = 0; r < 4; r++)
    for (int off = 32; off > 0; off >>= 1)
      m[r] = fmaxf(m[r], __shfl_xor(m[r], off, 64));
  __shared__ f32x4 red[4];
  int w = threadIdx.x >> 6;
  if ((threadIdx.x & 63) == 0) red[w] = f32x4{m[0], m[1], m[2], m[3]};
  __syncthreads();
  if (threadIdx.x == 0) {
    for (int r = 0; r < 4; r++) {
      float mr = fmaxf(fmaxf(red[0][r], red[1][r]), fmaxf(red[2][r], red[3][r]));
      kmax[(size_t)n * Ppad + p0 + r] = __expf(mr);
    }
  }
}

// loss = 0.5 * sum_n -log(mean_p kmax3) + 1.0 * sum_n -log(mean_p kmax4)
__global__ void final_kernel(const float* __restrict__ kmax3, const float* __restrict__ kmax4,
                             float* __restrict__ out)
{
  __shared__ float red[256];
  int tid = threadIdx.x;
  float total = 0.f;
  for (int l = 0; l < 2; l++) {
    const float* km = l ? kmax4 : kmax3;
    int P = l ? 784 : 3136;
    int Ppad = l ? 896 : 3200;
    float wgt = l ? 1.0f : 0.5f;
    for (int n = 0; n < 4; n++) {
      float s = 0.f;
      for (int i = tid; i < P; i += 256) s += km[(size_t)n * Ppad + i];
      red[tid] = s;
      __syncthreads();
      for (int st = 128; st > 0; st >>= 1) {
        if (tid < st) red[tid] += red[tid + st];
        __syncthreads();
      }
      if (tid == 0) total += wgt * (-logf(red[0] / (float)P));
      __syncthreads();
    }
  }
  if (tid == 0) out[0] = total;
}

extern "C" void kernel_launch(void* const* d_in, const int* in_sizes, int n_in,
                              void* d_out, int out_size, void* d_ws, size_t ws_size,
                              hipStream_t stream)
{
  const float* gen3 = (const float*)d_in[0];
  const float* tar3 = (const float*)d_in[1];
  const float* gen4 = (const float*)d_in[2];
  const float* tar4 = (const float*)d_in[3];

  // Layer3: C=256, P=3136, pad 3200 (25*128). Layer4: C=512, P=784, pad 896 (7*128).
  char* ws = (char*)d_ws;
  size_t off = 0;
  auto take = [&](size_t bytes) { char* p = ws + off; off += bytes; return p; };

  // ---- zeroed region (one contiguous memset) ----
  unsigned* divkey3 = (unsigned*)take(51200);   // 4*3200*4
  float*  Z3    = (float*) take(51200);
  unsigned* divkey4 = (unsigned*)take(14336);   // 4*896*4
  float*  Z4    = (float*) take(14336);
  float*  acc3  = (float*) take(204800);        // 4*3200*16
  float*  acc4  = (float*) take(57344);         // 4*896*16
  size_t zero_bytes = off;
  // ---- rest ----
  __bf16* That3 = (__bf16*)take(6553600);       // 4*3200*256*2
  __bf16* Ghat3 = (__bf16*)take(6553600);
  __bf16* That4 = (__bf16*)take(3670016);       // 4*896*512*2
  __bf16* Ghat4 = (__bf16*)take(3670016);
  __bf16* S3    = (__bf16*)take(81920000);      // 4*3200*3200*2
  __bf16* S4    = (__bf16*)take(6422528);       // 4*896*896*2
  float* invd3  = (float*)take(51200);
  float* c3     = (float*)take(51200);
  float* kmax3  = (float*)take(51200);
  float* invd4  = (float*)take(14336);
  float* c4     = (float*)take(14336);
  float* kmax4  = (float*)take(14336);

  hipMemsetAsync(divkey3, 0, zero_bytes, stream);

  stats_kernel<<<dim3(49, 8, 4), 256, 0, stream>>>(gen3, tar3, acc3, 256, 3136, 3200);
  stats_kernel<<<dim3(13, 16, 4), 256, 0, stream>>>(gen4, tar4, acc4, 512, 784, 896);

  apply_kernel<<<dim3(13, 32, 4), 256, 0, stream>>>(gen3, tar3, acc3, Ghat3, That3, 256, 3136, 3200);
  apply_kernel<<<dim3(4, 64, 4), 256, 0, stream>>>(gen4, tar4, acc4, Ghat4, That4, 512, 784, 896);

  gemm_kernel<<<dim3(25, 25, 4), 256, 0, stream>>>(That3, Ghat3, S3, divkey3, 256, 3200, 3200, 3136);
  gemm_kernel<<<dim3(7, 7, 4), 256, 0, stream>>>(That4, Ghat4, S4, divkey4, 512, 896, 896, 784);

  invd_kernel<<<dim3(13, 4), 256, 0, stream>>>(divkey3, invd3, 3136, 3200);
  invd_kernel<<<dim3(4, 4), 256, 0, stream>>>(divkey4, invd4, 784, 896);

  z_kernel<<<dim3(2, 32, 4), 256, 0, stream>>>(S3, invd3, Z3, 3136, 3200, 3136, 3200, 98);
  z_kernel<<<dim3(1, 16, 4), 256, 0, stream>>>(S4, invd4, Z4, 784, 896, 784, 896, 49);

  prep_kernel<<<dim3(13, 4), 256, 0, stream>>>(Z3, invd3, c3, 3136, 3200);
  prep_kernel<<<dim3(4, 4), 256, 0, stream>>>(Z4, invd4, c4, 784, 896);

  rowmax_kernel<<<dim3(784, 4), 256, 0, stream>>>(S3, invd3, c3, kmax3, 3136, 3200, 3200);
  rowmax_kernel<<<dim3(196, 4), 256, 0, stream>>>(S4, invd4, c4, kmax4, 784, 896, 896);

  final_kernel<<<1, 256, 0, stream>>>(kmax3, kmax4, (float*)d_out);
}

// Round 4
// 269.853 us; speedup vs baseline: 2.2036x; 1.0852x over previous
//
#include <hip/hip_runtime.h>
#include <math.h>

typedef __bf16 bf16x8 __attribute__((ext_vector_type(8)));
typedef float f32x4 __attribute__((ext_vector_type(4)));

#define EPSV 1e-5f
#define GLB(p) ((__attribute__((address_space(1))) void*)(p))
#define LDS(p) ((__attribute__((address_space(3))) void*)(p))

__device__ __forceinline__ unsigned fkey(float f) {
  unsigned b = __float_as_uint(f);
  return (b & 0x80000000u) ? ~b : (b | 0x80000000u);
}
__device__ __forceinline__ float funkey(unsigned k) {
  return __uint_as_float((k & 0x80000000u) ? (k & 0x7fffffffu) : ~k);
}

// ---- merged stats: per-pixel sums (st,sst,sg,ssg) via atomics ----
// grid (49,16,8): z>>2 selects layer, z&3 = n.
__global__ __launch_bounds__(256) void stats_kernel(
    const float* __restrict__ g3, const float* __restrict__ t3, float* __restrict__ a3,
    const float* __restrict__ g4, const float* __restrict__ t4, float* __restrict__ a4)
{
  int lay = blockIdx.z >> 2, n = blockIdx.z & 3;
  const float *gen, *tar; float* acc; int C, P, Ppad, NX, NY;
  if (lay == 0) { gen = g3; tar = t3; acc = a3; C = 256; P = 3136; Ppad = 3200; NX = 49; NY = 8; }
  else          { gen = g4; tar = t4; acc = a4; C = 512; P = 784;  Ppad = 896;  NX = 13; NY = 16; }
  if (blockIdx.x >= (unsigned)NX || blockIdx.y >= (unsigned)NY) return;
  int pl = threadIdx.x & 63, g = threadIdx.x >> 6;
  int p = blockIdx.x * 64 + pl;
  int c0 = blockIdx.y * 32 + g * 8;
  float st = 0.f, sst = 0.f, sg = 0.f, ssg = 0.f;
  if (p < P) {
    const float* tb = tar + (size_t)n * C * P + (size_t)c0 * P + p;
    const float* gb = gen + (size_t)n * C * P + (size_t)c0 * P + p;
    for (int j = 0; j < 8; j++) {
      float t = tb[(size_t)j * P];
      float gv = gb[(size_t)j * P];
      st += t; sst += t * t; sg += gv; ssg += gv * gv;
    }
  }
  __shared__ f32x4 red[4][64];
  red[g][pl] = f32x4{st, sst, sg, ssg};
  __syncthreads();
  if (g == 0 && p < P) {
    for (int k = 1; k < 4; k++) {
      f32x4 r = red[k][pl];
      st += r[0]; sst += r[1]; sg += r[2]; ssg += r[3];
    }
    float* a = acc + ((size_t)n * Ppad + p) * 4;
    atomicAdd(a + 0, st);
    atomicAdd(a + 1, sst);
    atomicAdd(a + 2, sg);
    atomicAdd(a + 3, ssg);
  }
}

// ---- merged apply: normalize, write bf16 [N][Ppad][C], zero pad rows ----
// grid (13,64,8)
__global__ __launch_bounds__(256) void apply_kernel(
    const float* __restrict__ g3, const float* __restrict__ t3, const float* __restrict__ a3,
    __bf16* __restrict__ G3, __bf16* __restrict__ T3,
    const float* __restrict__ g4, const float* __restrict__ t4, const float* __restrict__ a4,
    __bf16* __restrict__ G4, __bf16* __restrict__ T4)
{
  int lay = blockIdx.z >> 2, n = blockIdx.z & 3;
  const float *gen, *tar, *acc; __bf16 *Ghat, *That; int C, P, Ppad, NX, NY;
  if (lay == 0) { gen = g3; tar = t3; acc = a3; Ghat = G3; That = T3; C = 256; P = 3136; Ppad = 3200; NX = 13; NY = 32; }
  else          { gen = g4; tar = t4; acc = a4; Ghat = G4; That = T4; C = 512; P = 784;  Ppad = 896;  NX = 4;  NY = 64; }
  if (blockIdx.x >= (unsigned)NX || blockIdx.y >= (unsigned)NY) return;
  int p = blockIdx.x * 256 + threadIdx.x;
  int c0 = blockIdx.y * 8;
  if (p >= Ppad) return;
  __bf16* tp = That + ((size_t)n * Ppad + p) * C + c0;
  __bf16* gp = Ghat + ((size_t)n * Ppad + p) * C + c0;
  if (p >= P) {
    bf16x8 z;
    for (int j = 0; j < 8; j++) z[j] = (__bf16)0.f;
    *(bf16x8*)tp = z;
    *(bf16x8*)gp = z;
    return;
  }
  const float* a = acc + ((size_t)n * Ppad + p) * 4;
  float st = a[0], sst = a[1], sg = a[2], ssg = a[3];
  float m = st / (float)C;
  float vt = sst - st * st / (float)C;
  float vg = ssg - 2.f * m * sg + (float)C * m * m;
  float it = rsqrtf(fmaxf(vt, 1e-30f));
  float ig = rsqrtf(fmaxf(vg, 1e-30f));
  const float* tb = tar + (size_t)n * C * P + (size_t)c0 * P + p;
  const float* gb = gen + (size_t)n * C * P + (size_t)c0 * P + p;
  bf16x8 tv, gv;
  for (int j = 0; j < 8; j++) {
    tv[j] = (__bf16)((tb[(size_t)j * P] - m) * it);
    gv[j] = (__bf16)((gb[(size_t)j * P] - m) * ig);
  }
  *(bf16x8*)tp = tv;
  *(bf16x8*)gp = gv;
}

// ---- merged GEMM: 128x128 tile, BK=32, double-buffered LDS, 1 barrier/iter,
// XOR bank swizzle (slot = chunk ^ ((row>>1)&3)), bf16 S + colmax atomics ----
// grid (25,25,8)
__global__ __launch_bounds__(256) void gemm_kernel(
    const __bf16* __restrict__ A3, const __bf16* __restrict__ B3,
    __bf16* __restrict__ So3, unsigned* __restrict__ dk3,
    const __bf16* __restrict__ A4, const __bf16* __restrict__ B4,
    __bf16* __restrict__ So4, unsigned* __restrict__ dk4)
{
  __shared__ __attribute__((aligned(16))) __bf16 As[2][4096];
  __shared__ __attribute__((aligned(16))) __bf16 Bs[2][4096];
  int lay = blockIdx.z >> 2, n = blockIdx.z & 3;
  const __bf16 *A, *B; __bf16* S; unsigned* dk; int C, Ppad, Qpad, Preal, NT;
  if (lay == 0) { A = A3; B = B3; S = So3; dk = dk3; C = 256; Ppad = 3200; Qpad = 3200; Preal = 3136; NT = 25; }
  else          { A = A4; B = B4; S = So4; dk = dk4; C = 512; Ppad = 896;  Qpad = 896;  Preal = 784;  NT = 7; }
  if (blockIdx.x >= (unsigned)NT || blockIdx.y >= (unsigned)NT) return;
  int p0 = blockIdx.y * 128, q0 = blockIdx.x * 128;
  int tid = threadIdx.x;
  int w = tid >> 6, lane = tid & 63;
  int lm = lane & 15, lq = lane >> 4;
  int wrow = (w >> 1) * 64, wcol = (w & 1) * 64;

  // staging: thread t -> LDS slot t*16 B = row t>>2, chunk-slot t&3.
  // slot s of row r holds global chunk s ^ ((r>>1)&3)  (bank swizzle).
  int srow = tid >> 2;
  int scol = (((tid & 3) ^ ((tid >> 3) & 3)) * 8);
  const __bf16* gA = A + ((size_t)n * Ppad + p0 + srow) * C + scol;
  const __bf16* gB = B + ((size_t)n * Qpad + q0 + srow) * C + scol;
  size_t rowoff = (size_t)64 * C;

  // fragment read: row R=(wrow|wcol)+i*16+lm, want chunk lq -> slot lq^((R>>1)&3)
  int sl = lq ^ ((lm >> 1) & 3);
  int aoff = (wrow + lm) * 64 + sl * 16;  // bytes; +i*1024 per i-tile
  int boff = (wcol + lm) * 64 + sl * 16;

  f32x4 acc[4][4];
  for (int i = 0; i < 4; i++)
    for (int j = 0; j < 4; j++)
      acc[i][j] = f32x4{0.f, 0.f, 0.f, 0.f};

  char* lA0 = (char*)&As[0][0] + w * 1024;
  char* lB0 = (char*)&Bs[0][0] + w * 1024;

  // prologue: stage k=0 into buf 0
  __builtin_amdgcn_global_load_lds(GLB(gA), LDS(lA0), 16, 0, 0);
  __builtin_amdgcn_global_load_lds(GLB(gA + rowoff), LDS(lA0 + 4096), 16, 0, 0);
  __builtin_amdgcn_global_load_lds(GLB(gB), LDS(lB0), 16, 0, 0);
  __builtin_amdgcn_global_load_lds(GLB(gB + rowoff), LDS(lB0 + 4096), 16, 0, 0);

  int nk = C >> 5;
  for (int it = 0; it < nk; it++) {
    __syncthreads();  // drains the loads for buf it&1 (issued one iter ago)
    if (it + 1 < nk) {
      int k0 = (it + 1) << 5;
      char* a = lA0 + ((it + 1) & 1) * 8192;
      char* b = lB0 + ((it + 1) & 1) * 8192;
      __builtin_amdgcn_global_load_lds(GLB(gA + k0), LDS(a), 16, 0, 0);
      __builtin_amdgcn_global_load_lds(GLB(gA + rowoff + k0), LDS(a + 4096), 16, 0, 0);
      __builtin_amdgcn_global_load_lds(GLB(gB + k0), LDS(b), 16, 0, 0);
      __builtin_amdgcn_global_load_lds(GLB(gB + rowoff + k0), LDS(b + 4096), 16, 0, 0);
    }
    const char* ab = (const char*)&As[0][0] + (it & 1) * 8192;
    const char* bb = (const char*)&Bs[0][0] + (it & 1) * 8192;
    bf16x8 af[4], bf[4];
    for (int i = 0; i < 4; i++) af[i] = *(const bf16x8*)(ab + aoff + i * 1024);
    for (int j = 0; j < 4; j++) bf[j] = *(const bf16x8*)(bb + boff + j * 1024);
    for (int i = 0; i < 4; i++)
      for (int j = 0; j < 4; j++)
        acc[i][j] = __builtin_amdgcn_mfma_f32_16x16x32_bf16(af[i], bf[j], acc[i][j], 0, 0, 0);
  }

  // Epilogue: D row = lq*4+ri, col = lm (per 16x16 sub-tile)
  __bf16* Sb = S + (size_t)n * Ppad * Qpad;
  float cm[4] = {-INFINITY, -INFINITY, -INFINITY, -INFINITY};
  for (int i = 0; i < 4; i++) {
    for (int j = 0; j < 4; j++) {
      for (int ri = 0; ri < 4; ri++) {
        int pr = p0 + wrow + i * 16 + lq * 4 + ri;
        int qc = q0 + wcol + j * 16 + lm;
        __bf16 bv = (__bf16)acc[i][j][ri];
        Sb[(size_t)pr * Qpad + qc] = bv;
        if (pr < Preal) cm[j] = fmaxf(cm[j], (float)bv);
      }
    }
  }
  for (int j = 0; j < 4; j++) {
    float v = cm[j];
    v = fmaxf(v, __shfl_xor(v, 16, 64));
    v = fmaxf(v, __shfl_xor(v, 32, 64));
    if (lq == 0 && v > -INFINITY) {
      int qc = q0 + wcol + j * 16 + lm;
      atomicMax(&dk[(size_t)n * Qpad + qc], fkey(v));
    }
  }
}

// ---- merged z: invd from divkey inline; Z[q] = sum_p exp((S-1)*invd) ----
// grid (2,98,8); writes invd (blocks with y==0)
__global__ __launch_bounds__(256) void z_kernel(
    const __bf16* __restrict__ S3, const unsigned* __restrict__ dk3,
    float* __restrict__ invd3, float* __restrict__ Z3,
    const __bf16* __restrict__ S4, const unsigned* __restrict__ dk4,
    float* __restrict__ invd4, float* __restrict__ Z4)
{
  int lay = blockIdx.z >> 2, n = blockIdx.z & 3;
  const __bf16* S; const unsigned* dk; float *invd, *Z;
  int Preal, Ppad, Qreal, Qpad, NX, NY;
  if (lay == 0) { S = S3; dk = dk3; invd = invd3; Z = Z3; Preal = 3136; Ppad = 3200; Qreal = 3136; Qpad = 3200; NX = 2; NY = 98; }
  else          { S = S4; dk = dk4; invd = invd4; Z = Z4; Preal = 784;  Ppad = 896;  Qreal = 784;  Qpad = 896;  NX = 1; NY = 25; }
  if (blockIdx.x >= (unsigned)NX || blockIdx.y >= (unsigned)NY) return;
  int q = (blockIdx.x * 256 + threadIdx.x) * 8;
  if (q >= Qreal) return;
  int p0 = blockIdx.y * 32, p1 = min(p0 + 32, Preal);
  float id[8], nid[8];
  for (int j = 0; j < 8; j++) {
    float mx = funkey(dk[(size_t)n * Qpad + q + j]);
    float d = 0.5f * (1.f - mx) + EPSV;
    id[j] = 1.f / d;
    nid[j] = -id[j];
  }
  if (blockIdx.y == 0)
    for (int j = 0; j < 8; j++) invd[(size_t)n * Qpad + q + j] = id[j];
  const __bf16* Sp = S + (size_t)n * Ppad * Qpad + q;
  float acc[8] = {0.f, 0.f, 0.f, 0.f, 0.f, 0.f, 0.f, 0.f};
  for (int p = p0; p < p1; p += 4) {
    bf16x8 s0 = *(const bf16x8*)(Sp + (size_t)p * Qpad);
    bf16x8 s1 = *(const bf16x8*)(Sp + (size_t)(p + 1) * Qpad);
    bf16x8 s2 = *(const bf16x8*)(Sp + (size_t)(p + 2) * Qpad);
    bf16x8 s3 = *(const bf16x8*)(Sp + (size_t)(p + 3) * Qpad);
    for (int j = 0; j < 8; j++) acc[j] += __expf(fmaf((float)s0[j], id[j], nid[j]));
    for (int j = 0; j < 8; j++) acc[j] += __expf(fmaf((float)s1[j], id[j], nid[j]));
    for (int j = 0; j < 8; j++) acc[j] += __expf(fmaf((float)s2[j], id[j], nid[j]));
    for (int j = 0; j < 8; j++) acc[j] += __expf(fmaf((float)s3[j], id[j], nid[j]));
  }
  float* zp = Z + (size_t)n * Qpad + q;
  for (int j = 0; j < 8; j++) atomicAdd(zp + j, acc[j]);
}

// ---- merged rowmax: kmax[p] = exp(max_q (S*invd - invd - log Z)) ----
// grid (784,8); 4 rows/block
__global__ __launch_bounds__(256) void rowmax_kernel(
    const __bf16* __restrict__ S3, const float* __restrict__ invd3,
    const float* __restrict__ Z3, float* __restrict__ km3,
    const __bf16* __restrict__ S4, const float* __restrict__ invd4,
    const float* __restrict__ Z4, float* __restrict__ km4)
{
  int lay = blockIdx.y >> 2, n = blockIdx.y & 3;
  const __bf16* S; const float *invd, *Z; float* kmax;
  int Qreal, Qpad, Ppad, NB;
  if (lay == 0) { S = S3; invd = invd3; Z = Z3; kmax = km3; Qreal = 3136; Qpad = 3200; Ppad = 3200; NB = 784; }
  else          { S = S4; invd = invd4; Z = Z4; kmax = km4; Qreal = 784;  Qpad = 896;  Ppad = 896;  NB = 196; }
  if (blockIdx.x >= (unsigned)NB) return;
  int p0 = blockIdx.x * 4;
  const __bf16* Sp = S + ((size_t)n * Ppad + p0) * Qpad;
  const float* id = invd + (size_t)n * Qpad;
  const float* zz = Z + (size_t)n * Qpad;
  int nq8 = Qreal >> 3;
  float m[4] = {-INFINITY, -INFINITY, -INFINITY, -INFINITY};
  for (int i = threadIdx.x; i < nq8; i += 256) {
    f32x4 i0 = *(const f32x4*)(id + (size_t)i * 8);
    f32x4 i1 = *(const f32x4*)(id + (size_t)i * 8 + 4);
    f32x4 z0 = *(const f32x4*)(zz + (size_t)i * 8);
    f32x4 z1 = *(const f32x4*)(zz + (size_t)i * 8 + 4);
    f32x4 c0, c1;
    for (int j = 0; j < 4; j++) { c0[j] = -__logf(z0[j]) - i0[j]; c1[j] = -__logf(z1[j]) - i1[j]; }
    for (int r = 0; r < 4; r++) {
      bf16x8 sv = *(const bf16x8*)(Sp + (size_t)r * Qpad + (size_t)i * 8);
      for (int j = 0; j < 4; j++)
        m[r] = fmaxf(m[r], fmaf((float)sv[j], i0[j], c0[j]));
      for (int j = 0; j < 4; j++)
        m[r] = fmaxf(m[r], fmaf((float)sv[j + 4], i1[j], c1[j]));
    }
  }
  for (int r = 0; r < 4; r++)
    for (int off = 32; off > 0; off >>= 1)
      m[r] = fmaxf(m[r], __shfl_xor(m[r], off, 64));
  __shared__ f32x4 red[4];
  int w = threadIdx.x >> 6;
  if ((threadIdx.x & 63) == 0) red[w] = f32x4{m[0], m[1], m[2], m[3]};
  __syncthreads();
  if (threadIdx.x == 0) {
    for (int r = 0; r < 4; r++) {
      float mr = fmaxf(fmaxf(red[0][r], red[1][r]), fmaxf(red[2][r], red[3][r]));
      kmax[(size_t)n * Ppad + p0 + r] = __expf(mr);
    }
  }
}

// loss = 0.5 * sum_n -log(mean_p kmax3) + 1.0 * sum_n -log(mean_p kmax4)
__global__ void final_kernel(const float* __restrict__ kmax3, const float* __restrict__ kmax4,
                             float* __restrict__ out)
{
  __shared__ float red[256];
  int tid = threadIdx.x;
  float total = 0.f;
  for (int l = 0; l < 2; l++) {
    const float* km = l ? kmax4 : kmax3;
    int P = l ? 784 : 3136;
    int Ppad = l ? 896 : 3200;
    float wgt = l ? 1.0f : 0.5f;
    for (int n = 0; n < 4; n++) {
      float s = 0.f;
      for (int i = tid; i < P; i += 256) s += km[(size_t)n * Ppad + i];
      red[tid] = s;
      __syncthreads();
      for (int st = 128; st > 0; st >>= 1) {
        if (tid < st) red[tid] += red[tid + st];
        __syncthreads();
      }
      if (tid == 0) total += wgt * (-logf(red[0] / (float)P));
      __syncthreads();
    }
  }
  if (tid == 0) out[0] = total;
}

extern "C" void kernel_launch(void* const* d_in, const int* in_sizes, int n_in,
                              void* d_out, int out_size, void* d_ws, size_t ws_size,
                              hipStream_t stream)
{
  const float* gen3 = (const float*)d_in[0];
  const float* tar3 = (const float*)d_in[1];
  const float* gen4 = (const float*)d_in[2];
  const float* tar4 = (const float*)d_in[3];

  char* ws = (char*)d_ws;
  size_t off = 0;
  auto take = [&](size_t bytes) { char* p = ws + off; off += bytes; return p; };

  // ---- zeroed region (one contiguous memset) ----
  unsigned* divkey3 = (unsigned*)take(51200);   // 4*3200*4
  float*  Z3    = (float*) take(51200);
  unsigned* divkey4 = (unsigned*)take(14336);   // 4*896*4
  float*  Z4    = (float*) take(14336);
  float*  acc3  = (float*) take(204800);        // 4*3200*16
  float*  acc4  = (float*) take(57344);         // 4*896*16
  size_t zero_bytes = off;
  // ---- rest ----
  __bf16* That3 = (__bf16*)take(6553600);       // 4*3200*256*2
  __bf16* Ghat3 = (__bf16*)take(6553600);
  __bf16* That4 = (__bf16*)take(3670016);       // 4*896*512*2
  __bf16* Ghat4 = (__bf16*)take(3670016);
  __bf16* S3    = (__bf16*)take(81920000);      // 4*3200*3200*2
  __bf16* S4    = (__bf16*)take(6422528);       // 4*896*896*2
  float* invd3  = (float*)take(51200);
  float* kmax3  = (float*)take(51200);
  float* invd4  = (float*)take(14336);
  float* kmax4  = (float*)take(14336);

  hipMemsetAsync(divkey3, 0, zero_bytes, stream);

  stats_kernel<<<dim3(49, 16, 8), 256, 0, stream>>>(gen3, tar3, acc3, gen4, tar4, acc4);
  apply_kernel<<<dim3(13, 64, 8), 256, 0, stream>>>(gen3, tar3, acc3, Ghat3, That3,
                                                    gen4, tar4, acc4, Ghat4, That4);
  gemm_kernel<<<dim3(25, 25, 8), 256, 0, stream>>>(That3, Ghat3, S3, divkey3,
                                                   That4, Ghat4, S4, divkey4);
  z_kernel<<<dim3(2, 98, 8), 256, 0, stream>>>(S3, divkey3, invd3, Z3,
                                               S4, divkey4, invd4, Z4);
  rowmax_kernel<<<dim3(784, 8), 256, 0, stream>>>(S3, invd3, Z3, kmax3,
                                                  S4, invd4, Z4, kmax4);
  final_kernel<<<1, 256, 0, stream>>>(kmax3, kmax4, (float*)d_out);
}

// Round 5
// 224.628 us; speedup vs baseline: 2.6472x; 1.2013x over previous
//
#include <hip/hip_runtime.h>
#include <math.h>

typedef __bf16 bf16x8 __attribute__((ext_vector_type(8)));
typedef float f32x4 __attribute__((ext_vector_type(4)));

#define EPSV 1e-5f
#define GLB(p) ((__attribute__((address_space(1))) void*)(p))
#define LDS(p) ((__attribute__((address_space(3))) void*)(p))

__device__ __forceinline__ unsigned fkey(float f) {
  unsigned b = __float_as_uint(f);
  return (b & 0x80000000u) ? ~b : (b | 0x80000000u);
}
__device__ __forceinline__ float funkey(unsigned k) {
  return __uint_as_float((k & 0x80000000u) ? (k & 0x7fffffffu) : ~k);
}

// ---- single-pass norm: block owns p-tile x all C; stats in regs+LDS, then
// apply+store bf16 [N][Ppad][C]. Pad blocks (y>=NWORK) zero the pad rows. ----
// grid (1, 100, 8): z>>2 = layer, z&3 = n.
__global__ __launch_bounds__(256) void norm_kernel(
    const float* __restrict__ g3, const float* __restrict__ t3,
    __bf16* __restrict__ G3, __bf16* __restrict__ T3,
    const float* __restrict__ g4, const float* __restrict__ t4,
    __bf16* __restrict__ G4, __bf16* __restrict__ T4)
{
  int lay = blockIdx.z >> 2, n = blockIdx.z & 3;
  const float *gen, *tar; __bf16 *Gh, *Th; int C, P, Ppad, PT, NWORK, NTOT, NG;
  if (lay == 0) { gen = g3; tar = t3; Gh = G3; Th = T3; C = 256; P = 3136; Ppad = 3200; PT = 32; NWORK = 98; NTOT = 100; NG = 8; }
  else          { gen = g4; tar = t4; Gh = G4; Th = T4; C = 512; P = 784;  Ppad = 896;  PT = 16; NWORK = 49; NTOT = 56;  NG = 16; }
  if (blockIdx.y >= (unsigned)NTOT) return;
  int pl, cg;
  if (lay == 0) { pl = threadIdx.x & 31; cg = threadIdx.x >> 5; }
  else          { pl = threadIdx.x & 15; cg = threadIdx.x >> 4; }
  int c0 = cg * 32;

  if (blockIdx.y >= (unsigned)NWORK) {  // zero pad rows
    int p = P + (blockIdx.y - NWORK) * PT + pl;
    if (p < Ppad) {
      __bf16* tp = Th + ((size_t)n * Ppad + p) * C + c0;
      __bf16* gp = Gh + ((size_t)n * Ppad + p) * C + c0;
      bf16x8 z;
      for (int j = 0; j < 8; j++) z[j] = (__bf16)0.f;
      for (int j = 0; j < 32; j += 8) { *(bf16x8*)(tp + j) = z; *(bf16x8*)(gp + j) = z; }
    }
    return;
  }

  int p = blockIdx.y * PT + pl;
  const float* tb = tar + (size_t)n * C * P + (size_t)c0 * P + p;
  const float* gb = gen + (size_t)n * C * P + (size_t)c0 * P + p;
  float tv[32], gv[32];
  float st = 0.f, sst = 0.f, sg = 0.f, ssg = 0.f;
#pragma unroll
  for (int j = 0; j < 32; j++) {
    tv[j] = tb[(size_t)j * P];
    gv[j] = gb[(size_t)j * P];
  }
#pragma unroll
  for (int j = 0; j < 32; j++) {
    st += tv[j]; sst += tv[j] * tv[j];
    sg += gv[j]; ssg += gv[j] * gv[j];
  }
  __shared__ f32x4 red[16][32];
  red[cg][pl] = f32x4{st, sst, sg, ssg};
  __syncthreads();
  for (int h = NG >> 1; h > 0; h >>= 1) {
    if (cg < h) {
      f32x4 a = red[cg][pl], b = red[cg + h][pl];
      red[cg][pl] = f32x4{a[0] + b[0], a[1] + b[1], a[2] + b[2], a[3] + b[3]};
    }
    __syncthreads();
  }
  f32x4 s = red[0][pl];
  float m = s[0] / (float)C;
  float vt = s[1] - s[0] * s[0] / (float)C;
  float vg = s[3] - 2.f * m * s[2] + (float)C * m * m;
  float it = rsqrtf(fmaxf(vt, 1e-30f));
  float ig = rsqrtf(fmaxf(vg, 1e-30f));
  __bf16* tp = Th + ((size_t)n * Ppad + p) * C + c0;
  __bf16* gp = Gh + ((size_t)n * Ppad + p) * C + c0;
#pragma unroll
  for (int j0 = 0; j0 < 32; j0 += 8) {
    bf16x8 to, go;
    for (int j = 0; j < 8; j++) {
      to[j] = (__bf16)((tv[j0 + j] - m) * it);
      go[j] = (__bf16)((gv[j0 + j] - m) * ig);
    }
    *(bf16x8*)(tp + j0) = to;
    *(bf16x8*)(gp + j0) = go;
  }
}

// ---- merged GEMM: 128x128 tile, BK=32, double-buffered LDS, 1 barrier/iter,
// XOR bank swizzle, bf16 S + colmax atomics ---- grid (25,25,8)
__global__ __launch_bounds__(256) void gemm_kernel(
    const __bf16* __restrict__ A3, const __bf16* __restrict__ B3,
    __bf16* __restrict__ So3, unsigned* __restrict__ dk3,
    const __bf16* __restrict__ A4, const __bf16* __restrict__ B4,
    __bf16* __restrict__ So4, unsigned* __restrict__ dk4)
{
  __shared__ __attribute__((aligned(16))) __bf16 As[2][4096];
  __shared__ __attribute__((aligned(16))) __bf16 Bs[2][4096];
  int lay = blockIdx.z >> 2, n = blockIdx.z & 3;
  const __bf16 *A, *B; __bf16* S; unsigned* dk; int C, Ppad, Qpad, Preal, NT;
  if (lay == 0) { A = A3; B = B3; S = So3; dk = dk3; C = 256; Ppad = 3200; Qpad = 3200; Preal = 3136; NT = 25; }
  else          { A = A4; B = B4; S = So4; dk = dk4; C = 512; Ppad = 896;  Qpad = 896;  Preal = 784;  NT = 7; }
  if (blockIdx.x >= (unsigned)NT || blockIdx.y >= (unsigned)NT) return;
  int p0 = blockIdx.y * 128, q0 = blockIdx.x * 128;
  int tid = threadIdx.x;
  int w = tid >> 6, lane = tid & 63;
  int lm = lane & 15, lq = lane >> 4;
  int wrow = (w >> 1) * 64, wcol = (w & 1) * 64;

  int srow = tid >> 2;
  int scol = (((tid & 3) ^ ((tid >> 3) & 3)) * 8);
  const __bf16* gA = A + ((size_t)n * Ppad + p0 + srow) * C + scol;
  const __bf16* gB = B + ((size_t)n * Qpad + q0 + srow) * C + scol;
  size_t rowoff = (size_t)64 * C;

  int sl = lq ^ ((lm >> 1) & 3);
  int aoff = (wrow + lm) * 64 + sl * 16;
  int boff = (wcol + lm) * 64 + sl * 16;

  f32x4 acc[4][4];
  for (int i = 0; i < 4; i++)
    for (int j = 0; j < 4; j++)
      acc[i][j] = f32x4{0.f, 0.f, 0.f, 0.f};

  char* lA0 = (char*)&As[0][0] + w * 1024;
  char* lB0 = (char*)&Bs[0][0] + w * 1024;

  __builtin_amdgcn_global_load_lds(GLB(gA), LDS(lA0), 16, 0, 0);
  __builtin_amdgcn_global_load_lds(GLB(gA + rowoff), LDS(lA0 + 4096), 16, 0, 0);
  __builtin_amdgcn_global_load_lds(GLB(gB), LDS(lB0), 16, 0, 0);
  __builtin_amdgcn_global_load_lds(GLB(gB + rowoff), LDS(lB0 + 4096), 16, 0, 0);

  int nk = C >> 5;
  for (int it = 0; it < nk; it++) {
    __syncthreads();
    if (it + 1 < nk) {
      int k0 = (it + 1) << 5;
      char* a = lA0 + ((it + 1) & 1) * 8192;
      char* b = lB0 + ((it + 1) & 1) * 8192;
      __builtin_amdgcn_global_load_lds(GLB(gA + k0), LDS(a), 16, 0, 0);
      __builtin_amdgcn_global_load_lds(GLB(gA + rowoff + k0), LDS(a + 4096), 16, 0, 0);
      __builtin_amdgcn_global_load_lds(GLB(gB + k0), LDS(b), 16, 0, 0);
      __builtin_amdgcn_global_load_lds(GLB(gB + rowoff + k0), LDS(b + 4096), 16, 0, 0);
    }
    const char* ab = (const char*)&As[0][0] + (it & 1) * 8192;
    const char* bb = (const char*)&Bs[0][0] + (it & 1) * 8192;
    bf16x8 af[4], bf[4];
    for (int i = 0; i < 4; i++) af[i] = *(const bf16x8*)(ab + aoff + i * 1024);
    for (int j = 0; j < 4; j++) bf[j] = *(const bf16x8*)(bb + boff + j * 1024);
    for (int i = 0; i < 4; i++)
      for (int j = 0; j < 4; j++)
        acc[i][j] = __builtin_amdgcn_mfma_f32_16x16x32_bf16(af[i], bf[j], acc[i][j], 0, 0, 0);
  }

  __bf16* Sb = S + (size_t)n * Ppad * Qpad;
  float cm[4] = {-INFINITY, -INFINITY, -INFINITY, -INFINITY};
  for (int i = 0; i < 4; i++) {
    for (int j = 0; j < 4; j++) {
      for (int ri = 0; ri < 4; ri++) {
        int pr = p0 + wrow + i * 16 + lq * 4 + ri;
        int qc = q0 + wcol + j * 16 + lm;
        __bf16 bv = (__bf16)acc[i][j][ri];
        Sb[(size_t)pr * Qpad + qc] = bv;
        if (pr < Preal) cm[j] = fmaxf(cm[j], (float)bv);
      }
    }
  }
  for (int j = 0; j < 4; j++) {
    float v = cm[j];
    v = fmaxf(v, __shfl_xor(v, 16, 64));
    v = fmaxf(v, __shfl_xor(v, 32, 64));
    if (lq == 0 && v > -INFINITY) {
      int qc = q0 + wcol + j * 16 + lm;
      atomicMax(&dk[(size_t)n * Qpad + qc], fkey(v));
    }
  }
}

// ---- z partials: block = q-tile(2048) x p-slab(32/16); NO atomics.
// Zp[n][slab][Qpad] plain coalesced stores. ---- grid (2,98,8)
__global__ __launch_bounds__(256) void z_kernel(
    const __bf16* __restrict__ S3, const unsigned* __restrict__ dk3, float* __restrict__ Zp3,
    const __bf16* __restrict__ S4, const unsigned* __restrict__ dk4, float* __restrict__ Zp4)
{
  int lay = blockIdx.z >> 2, n = blockIdx.z & 3;
  const __bf16* S; const unsigned* dk; float* Zp;
  int Ppad, Qreal, Qpad, NSL, SLAB, NX;
  if (lay == 0) { S = S3; dk = dk3; Zp = Zp3; Ppad = 3200; Qreal = 3136; Qpad = 3200; NSL = 98; SLAB = 32; NX = 2; }
  else          { S = S4; dk = dk4; Zp = Zp4; Ppad = 896;  Qreal = 784;  Qpad = 896;  NSL = 49; SLAB = 16; NX = 1; }
  if (blockIdx.x >= (unsigned)NX || blockIdx.y >= (unsigned)NSL) return;
  int q = (blockIdx.x * 256 + threadIdx.x) * 8;
  if (q >= Qreal) return;
  float id[8], nid[8];
  const unsigned* dkp = dk + (size_t)n * Qpad + q;
#pragma unroll
  for (int j = 0; j < 8; j++) {
    float mx = funkey(dkp[j]);
    float d = 0.5f * (1.f - mx) + EPSV;
    id[j] = 1.f / d;
    nid[j] = -id[j];
  }
  int p0 = blockIdx.y * SLAB;
  const __bf16* Sp = S + (size_t)n * Ppad * Qpad + q;
  float acc[8] = {0.f, 0.f, 0.f, 0.f, 0.f, 0.f, 0.f, 0.f};
  for (int pb = 0; pb < SLAB; pb += 8) {
    bf16x8 sv[8];
#pragma unroll
    for (int r = 0; r < 8; r++)
      sv[r] = *(const bf16x8*)(Sp + (size_t)(p0 + pb + r) * Qpad);
#pragma unroll
    for (int r = 0; r < 8; r++)
      for (int j = 0; j < 8; j++)
        acc[j] += __expf(fmaf((float)sv[r][j], id[j], nid[j]));
  }
  float* zp = Zp + ((size_t)n * NSL + blockIdx.y) * Qpad + q;
  *(f32x4*)zp = f32x4{acc[0], acc[1], acc[2], acc[3]};
  *(f32x4*)(zp + 4) = f32x4{acc[4], acc[5], acc[6], acc[7]};
}

// ---- reduce: Z[q] = sum_slab Zp ; invd[q] ; c[q] = -log(Z)-invd ---- grid (13,8)
__global__ __launch_bounds__(256) void reduce_kernel(
    const float* __restrict__ Zp3, const unsigned* __restrict__ dk3,
    float* __restrict__ invd3, float* __restrict__ c3,
    const float* __restrict__ Zp4, const unsigned* __restrict__ dk4,
    float* __restrict__ invd4, float* __restrict__ c4)
{
  int lay = blockIdx.y >> 2, n = blockIdx.y & 3;
  const float* Zp; const unsigned* dk; float *invd, *c; int Qreal, Qpad, NSL;
  if (lay == 0) { Zp = Zp3; dk = dk3; invd = invd3; c = c3; Qreal = 3136; Qpad = 3200; NSL = 98; }
  else          { Zp = Zp4; dk = dk4; invd = invd4; c = c4; Qreal = 784;  Qpad = 896;  NSL = 49; }
  int q = blockIdx.x * 256 + threadIdx.x;
  if (q >= Qreal) return;
  float s = 0.f;
  for (int sl = 0; sl < NSL; sl++)
    s += Zp[((size_t)n * NSL + sl) * Qpad + q];
  float mx = funkey(dk[(size_t)n * Qpad + q]);
  float d = 0.5f * (1.f - mx) + EPSV;
  float idv = 1.f / d;
  invd[(size_t)n * Qpad + q] = idv;
  c[(size_t)n * Qpad + q] = -logf(s) - idv;
}

// ---- rowmax: kmax[p] = exp(max_q (S*invd + c)) ; 4 rows/block ---- grid (784,8)
__global__ __launch_bounds__(256) void rowmax_kernel(
    const __bf16* __restrict__ S3, const float* __restrict__ invd3,
    const float* __restrict__ c3, float* __restrict__ km3,
    const __bf16* __restrict__ S4, const float* __restrict__ invd4,
    const float* __restrict__ c4, float* __restrict__ km4)
{
  int lay = blockIdx.y >> 2, n = blockIdx.y & 3;
  const __bf16* S; const float *invd, *cc; float* kmax;
  int Qreal, Qpad, Ppad, NB;
  if (lay == 0) { S = S3; invd = invd3; cc = c3; kmax = km3; Qreal = 3136; Qpad = 3200; Ppad = 3200; NB = 784; }
  else          { S = S4; invd = invd4; cc = c4; kmax = km4; Qreal = 784;  Qpad = 896;  Ppad = 896;  NB = 196; }
  if (blockIdx.x >= (unsigned)NB) return;
  int p0 = blockIdx.x * 4;
  const __bf16* Sp = S + ((size_t)n * Ppad + p0) * Qpad;
  const float* id = invd + (size_t)n * Qpad;
  const float* cp = cc + (size_t)n * Qpad;
  int nq8 = Qreal >> 3;
  float m[4] = {-INFINITY, -INFINITY, -INFINITY, -INFINITY};
  for (int i = threadIdx.x; i < nq8; i += 256) {
    f32x4 i0 = *(const f32x4*)(id + (size_t)i * 8);
    f32x4 i1 = *(const f32x4*)(id + (size_t)i * 8 + 4);
    f32x4 c0 = *(const f32x4*)(cp + (size_t)i * 8);
    f32x4 c1 = *(const f32x4*)(cp + (size_t)i * 8 + 4);
    for (int r = 0; r < 4; r++) {
      bf16x8 sv = *(const bf16x8*)(Sp + (size_t)r * Qpad + (size_t)i * 8);
      for (int j = 0; j < 4; j++)
        m[r] = fmaxf(m[r], fmaf((float)sv[j], i0[j], c0[j]));
      for (int j = 0; j < 4; j++)
        m[r] = fmaxf(m[r], fmaf((float)sv[j + 4], i1[j], c1[j]));
    }
  }
  for (int r = 0; r < 4; r++)
    for (int off = 32; off > 0; off >>= 1)
      m[r] = fmaxf(m[r], __shfl_xor(m[r], off, 64));
  __shared__ f32x4 red[4];
  int w = threadIdx.x >> 6;
  if ((threadIdx.x & 63) == 0) red[w] = f32x4{m[0], m[1], m[2], m[3]};
  __syncthreads();
  if (threadIdx.x == 0) {
    for (int r = 0; r < 4; r++) {
      float mr = fmaxf(fmaxf(red[0][r], red[1][r]), fmaxf(red[2][r], red[3][r]));
      kmax[(size_t)n * Ppad + p0 + r] = __expf(mr);
    }
  }
}

// loss = 0.5 * sum_n -log(mean_p kmax3) + 1.0 * sum_n -log(mean_p kmax4)
__global__ void final_kernel(const float* __restrict__ kmax3, const float* __restrict__ kmax4,
                             float* __restrict__ out)
{
  __shared__ float red[256];
  int tid = threadIdx.x;
  float total = 0.f;
  for (int l = 0; l < 2; l++) {
    const float* km = l ? kmax4 : kmax3;
    int P = l ? 784 : 3136;
    int Ppad = l ? 896 : 3200;
    float wgt = l ? 1.0f : 0.5f;
    for (int n = 0; n < 4; n++) {
      float s = 0.f;
      for (int i = tid; i < P; i += 256) s += km[(size_t)n * Ppad + i];
      red[tid] = s;
      __syncthreads();
      for (int st = 128; st > 0; st >>= 1) {
        if (tid < st) red[tid] += red[tid + st];
        __syncthreads();
      }
      if (tid == 0) total += wgt * (-logf(red[0] / (float)P));
      __syncthreads();
    }
  }
  if (tid == 0) out[0] = total;
}

extern "C" void kernel_launch(void* const* d_in, const int* in_sizes, int n_in,
                              void* d_out, int out_size, void* d_ws, size_t ws_size,
                              hipStream_t stream)
{
  const float* gen3 = (const float*)d_in[0];
  const float* tar3 = (const float*)d_in[1];
  const float* gen4 = (const float*)d_in[2];
  const float* tar4 = (const float*)d_in[3];

  char* ws = (char*)d_ws;
  size_t off = 0;
  auto take = [&](size_t bytes) { char* p = ws + off; off += bytes; return p; };

  // ---- zeroed region (one contiguous memset) ----
  unsigned* divkey3 = (unsigned*)take(51200);   // 4*3200*4
  unsigned* divkey4 = (unsigned*)take(14336);   // 4*896*4
  size_t zero_bytes = off;                      // 65536
  // ---- rest ----
  __bf16* That3 = (__bf16*)take(6553600);       // 4*3200*256*2
  __bf16* Ghat3 = (__bf16*)take(6553600);
  __bf16* That4 = (__bf16*)take(3670016);       // 4*896*512*2
  __bf16* Ghat4 = (__bf16*)take(3670016);
  __bf16* S3    = (__bf16*)take(81920000);      // 4*3200*3200*2
  __bf16* S4    = (__bf16*)take(6422528);       // 4*896*896*2
  float*  Zp3   = (float*) take(5017600);       // 4*98*3200*4
  float*  Zp4   = (float*) take(702464);        // 4*49*896*4
  float* invd3  = (float*)take(51200);
  float* c3     = (float*)take(51200);
  float* kmax3  = (float*)take(51200);
  float* invd4  = (float*)take(14336);
  float* c4     = (float*)take(14336);
  float* kmax4  = (float*)take(14336);

  hipMemsetAsync(divkey3, 0, zero_bytes, stream);

  norm_kernel<<<dim3(1, 100, 8), 256, 0, stream>>>(gen3, tar3, Ghat3, That3,
                                                   gen4, tar4, Ghat4, That4);
  gemm_kernel<<<dim3(25, 25, 8), 256, 0, stream>>>(That3, Ghat3, S3, divkey3,
                                                   That4, Ghat4, S4, divkey4);
  z_kernel<<<dim3(2, 98, 8), 256, 0, stream>>>(S3, divkey3, Zp3,
                                               S4, divkey4, Zp4);
  reduce_kernel<<<dim3(13, 8), 256, 0, stream>>>(Zp3, divkey3, invd3, c3,
                                                 Zp4, divkey4, invd4, c4);
  rowmax_kernel<<<dim3(784, 8), 256, 0, stream>>>(S3, invd3, c3, kmax3,
                                                  S4, invd4, c4, kmax4);
  final_kernel<<<1, 256, 0, stream>>>(kmax3, kmax4, (float*)d_out);
}

// Round 6
// 219.701 us; speedup vs baseline: 2.7066x; 1.0224x over previous
//
#include <hip/hip_runtime.h>
#include <math.h>

typedef __bf16 bf16x8 __attribute__((ext_vector_type(8)));
typedef float f32x4 __attribute__((ext_vector_type(4)));

#define EPSV 1e-5f
#define GLB(p) ((__attribute__((address_space(1))) void*)(p))
#define LDS(p) ((__attribute__((address_space(3))) void*)(p))

__device__ __forceinline__ unsigned fkey(float f) {
  unsigned b = __float_as_uint(f);
  return (b & 0x80000000u) ? ~b : (b | 0x80000000u);
}
__device__ __forceinline__ float funkey(unsigned k) {
  return __uint_as_float((k & 0x80000000u) ? (k & 0x7fffffffu) : ~k);
}

// ---- single-pass norm: block owns p-tile x all C; stats in regs+LDS, then
// apply+store bf16 [N][Ppad][C]. Pad blocks (y>=NWORK) zero the pad rows. ----
// grid (1, 100, 8): z>>2 = layer, z&3 = n.
__global__ __launch_bounds__(256) void norm_kernel(
    const float* __restrict__ g3, const float* __restrict__ t3,
    __bf16* __restrict__ G3, __bf16* __restrict__ T3,
    const float* __restrict__ g4, const float* __restrict__ t4,
    __bf16* __restrict__ G4, __bf16* __restrict__ T4)
{
  int lay = blockIdx.z >> 2, n = blockIdx.z & 3;
  const float *gen, *tar; __bf16 *Gh, *Th; int C, P, Ppad, PT, NWORK, NTOT, NG;
  if (lay == 0) { gen = g3; tar = t3; Gh = G3; Th = T3; C = 256; P = 3136; Ppad = 3200; PT = 32; NWORK = 98; NTOT = 100; NG = 8; }
  else          { gen = g4; tar = t4; Gh = G4; Th = T4; C = 512; P = 784;  Ppad = 896;  PT = 16; NWORK = 49; NTOT = 56;  NG = 16; }
  if (blockIdx.y >= (unsigned)NTOT) return;
  int pl, cg;
  if (lay == 0) { pl = threadIdx.x & 31; cg = threadIdx.x >> 5; }
  else          { pl = threadIdx.x & 15; cg = threadIdx.x >> 4; }
  int c0 = cg * 32;

  if (blockIdx.y >= (unsigned)NWORK) {  // zero pad rows
    int p = P + (blockIdx.y - NWORK) * PT + pl;
    if (p < Ppad) {
      __bf16* tp = Th + ((size_t)n * Ppad + p) * C + c0;
      __bf16* gp = Gh + ((size_t)n * Ppad + p) * C + c0;
      bf16x8 z;
      for (int j = 0; j < 8; j++) z[j] = (__bf16)0.f;
      for (int j = 0; j < 32; j += 8) { *(bf16x8*)(tp + j) = z; *(bf16x8*)(gp + j) = z; }
    }
    return;
  }

  int p = blockIdx.y * PT + pl;
  const float* tb = tar + (size_t)n * C * P + (size_t)c0 * P + p;
  const float* gb = gen + (size_t)n * C * P + (size_t)c0 * P + p;
  float tv[32], gv[32];
  float st = 0.f, sst = 0.f, sg = 0.f, ssg = 0.f;
#pragma unroll
  for (int j = 0; j < 32; j++) {
    tv[j] = tb[(size_t)j * P];
    gv[j] = gb[(size_t)j * P];
  }
#pragma unroll
  for (int j = 0; j < 32; j++) {
    st += tv[j]; sst += tv[j] * tv[j];
    sg += gv[j]; ssg += gv[j] * gv[j];
  }
  __shared__ f32x4 red[16][32];
  red[cg][pl] = f32x4{st, sst, sg, ssg};
  __syncthreads();
  for (int h = NG >> 1; h > 0; h >>= 1) {
    if (cg < h) {
      f32x4 a = red[cg][pl], b = red[cg + h][pl];
      red[cg][pl] = f32x4{a[0] + b[0], a[1] + b[1], a[2] + b[2], a[3] + b[3]};
    }
    __syncthreads();
  }
  f32x4 s = red[0][pl];
  float m = s[0] / (float)C;
  float vt = s[1] - s[0] * s[0] / (float)C;
  float vg = s[3] - 2.f * m * s[2] + (float)C * m * m;
  float it = rsqrtf(fmaxf(vt, 1e-30f));
  float ig = rsqrtf(fmaxf(vg, 1e-30f));
  __bf16* tp = Th + ((size_t)n * Ppad + p) * C + c0;
  __bf16* gp = Gh + ((size_t)n * Ppad + p) * C + c0;
#pragma unroll
  for (int j0 = 0; j0 < 32; j0 += 8) {
    bf16x8 to, go;
    for (int j = 0; j < 8; j++) {
      to[j] = (__bf16)((tv[j0 + j] - m) * it);
      go[j] = (__bf16)((gv[j0 + j] - m) * ig);
    }
    *(bf16x8*)(tp + j0) = to;
    *(bf16x8*)(gp + j0) = go;
  }
}

// ---- GEMM: 128x128 tile, BK=32, 4-stage LDS pipeline with raw s_barrier +
// manual s_waitcnt vmcnt(N) (2 stages stay in flight across the barrier).
// XOR bank swizzle, bf16 S + colmax atomics ---- grid (25,25,8)
__global__ __launch_bounds__(256) void gemm_kernel(
    const __bf16* __restrict__ A3, const __bf16* __restrict__ B3,
    __bf16* __restrict__ So3, unsigned* __restrict__ dk3,
    const __bf16* __restrict__ A4, const __bf16* __restrict__ B4,
    __bf16* __restrict__ So4, unsigned* __restrict__ dk4)
{
  __shared__ __attribute__((aligned(16))) __bf16 As[4][4096];
  __shared__ __attribute__((aligned(16))) __bf16 Bs[4][4096];
  int lay = blockIdx.z >> 2, n = blockIdx.z & 3;
  const __bf16 *A, *B; __bf16* S; unsigned* dk; int C, Ppad, Qpad, Preal, NT;
  if (lay == 0) { A = A3; B = B3; S = So3; dk = dk3; C = 256; Ppad = 3200; Qpad = 3200; Preal = 3136; NT = 25; }
  else          { A = A4; B = B4; S = So4; dk = dk4; C = 512; Ppad = 896;  Qpad = 896;  Preal = 784;  NT = 7; }
  if (blockIdx.x >= (unsigned)NT || blockIdx.y >= (unsigned)NT) return;
  int p0 = blockIdx.y * 128, q0 = blockIdx.x * 128;
  int tid = threadIdx.x;
  int w = tid >> 6, lane = tid & 63;
  int lm = lane & 15, lq = lane >> 4;
  int wrow = (w >> 1) * 64, wcol = (w & 1) * 64;

  // staging: thread t -> LDS slot t*16 B (row t>>2, chunk-slot t&3);
  // slot s of row r holds global chunk s ^ ((r>>1)&3) (bank swizzle).
  int srow = tid >> 2;
  int scol = (((tid & 3) ^ ((tid >> 3) & 3)) * 8);
  const __bf16* gA = A + ((size_t)n * Ppad + p0 + srow) * C + scol;
  const __bf16* gB = B + ((size_t)n * Qpad + q0 + srow) * C + scol;
  size_t rowoff = (size_t)64 * C;
  char* lAbase = (char*)&As[0][0] + w * 1024;
  char* lBbase = (char*)&Bs[0][0] + w * 1024;

  // fragment read: row R=(wrow|wcol)+i*16+lm, chunk lq -> slot lq^((lm>>1)&3)
  int sl = lq ^ ((lm >> 1) & 3);
  int aoff = (wrow + lm) * 64 + sl * 16;  // bytes within a stage
  int boff = (wcol + lm) * 64 + sl * 16;

  f32x4 acc[4][4];
  for (int i = 0; i < 4; i++)
    for (int j = 0; j < 4; j++)
      acc[i][j] = f32x4{0.f, 0.f, 0.f, 0.f};

  auto issue = [&](int s) {
    int k0 = s << 5;
    char* a = lAbase + (s & 3) * 8192;
    char* b = lBbase + (s & 3) * 8192;
    __builtin_amdgcn_global_load_lds(GLB(gA + k0), LDS(a), 16, 0, 0);
    __builtin_amdgcn_global_load_lds(GLB(gA + rowoff + k0), LDS(a + 4096), 16, 0, 0);
    __builtin_amdgcn_global_load_lds(GLB(gB + k0), LDS(b), 16, 0, 0);
    __builtin_amdgcn_global_load_lds(GLB(gB + rowoff + k0), LDS(b + 4096), 16, 0, 0);
  };
  auto compute = [&](int it) {
    const char* ab = (const char*)&As[0][0] + (it & 3) * 8192;
    const char* bb = (const char*)&Bs[0][0] + (it & 3) * 8192;
    bf16x8 af[4], bf[4];
    for (int i = 0; i < 4; i++) af[i] = *(const bf16x8*)(ab + aoff + i * 1024);
    for (int j = 0; j < 4; j++) bf[j] = *(const bf16x8*)(bb + boff + j * 1024);
    for (int i = 0; i < 4; i++)
      for (int j = 0; j < 4; j++)
        acc[i][j] = __builtin_amdgcn_mfma_f32_16x16x32_bf16(af[i], bf[j], acc[i][j], 0, 0, 0);
  };

  int nk = C >> 5;  // 8 or 16
  issue(0); issue(1); issue(2);
  for (int it = 0; it < nk - 2; it++) {
    asm volatile("s_waitcnt vmcnt(8)" ::: "memory");  // stage `it` landed; 2 in flight
    __builtin_amdgcn_s_barrier();
    compute(it);
    if (it + 3 < nk) issue(it + 3);
  }
  asm volatile("s_waitcnt vmcnt(4)" ::: "memory");
  __builtin_amdgcn_s_barrier();
  compute(nk - 2);
  asm volatile("s_waitcnt vmcnt(0)" ::: "memory");
  __builtin_amdgcn_s_barrier();
  compute(nk - 1);

  // Epilogue: D row = lq*4+ri, col = lm (per 16x16 sub-tile)
  __bf16* Sb = S + (size_t)n * Ppad * Qpad;
  float cm[4] = {-INFINITY, -INFINITY, -INFINITY, -INFINITY};
  for (int i = 0; i < 4; i++) {
    for (int j = 0; j < 4; j++) {
      for (int ri = 0; ri < 4; ri++) {
        int pr = p0 + wrow + i * 16 + lq * 4 + ri;
        int qc = q0 + wcol + j * 16 + lm;
        __bf16 bv = (__bf16)acc[i][j][ri];
        Sb[(size_t)pr * Qpad + qc] = bv;
        if (pr < Preal) cm[j] = fmaxf(cm[j], (float)bv);
      }
    }
  }
  for (int j = 0; j < 4; j++) {
    float v = cm[j];
    v = fmaxf(v, __shfl_xor(v, 16, 64));
    v = fmaxf(v, __shfl_xor(v, 32, 64));
    if (lq == 0 && v > -INFINITY) {
      int qc = q0 + wcol + j * 16 + lm;
      atomicMax(&dk[(size_t)n * Qpad + qc], fkey(v));
    }
  }
}

// ---- z partials: block = q-tile(2048) x p-slab(32/16); NO atomics. ----
// grid (2,98,8)
__global__ __launch_bounds__(256) void z_kernel(
    const __bf16* __restrict__ S3, const unsigned* __restrict__ dk3, float* __restrict__ Zp3,
    const __bf16* __restrict__ S4, const unsigned* __restrict__ dk4, float* __restrict__ Zp4)
{
  int lay = blockIdx.z >> 2, n = blockIdx.z & 3;
  const __bf16* S; const unsigned* dk; float* Zp;
  int Ppad, Qreal, Qpad, NSL, SLAB, NX;
  if (lay == 0) { S = S3; dk = dk3; Zp = Zp3; Ppad = 3200; Qreal = 3136; Qpad = 3200; NSL = 98; SLAB = 32; NX = 2; }
  else          { S = S4; dk = dk4; Zp = Zp4; Ppad = 896;  Qreal = 784;  Qpad = 896;  NSL = 49; SLAB = 16; NX = 1; }
  if (blockIdx.x >= (unsigned)NX || blockIdx.y >= (unsigned)NSL) return;
  int q = (blockIdx.x * 256 + threadIdx.x) * 8;
  if (q >= Qreal) return;
  float id[8], nid[8];
  const unsigned* dkp = dk + (size_t)n * Qpad + q;
#pragma unroll
  for (int j = 0; j < 8; j++) {
    float mx = funkey(dkp[j]);
    float d = 0.5f * (1.f - mx) + EPSV;
    id[j] = 1.f / d;
    nid[j] = -id[j];
  }
  int p0 = blockIdx.y * SLAB;
  const __bf16* Sp = S + (size_t)n * Ppad * Qpad + q;
  float acc[8] = {0.f, 0.f, 0.f, 0.f, 0.f, 0.f, 0.f, 0.f};
  for (int pb = 0; pb < SLAB; pb += 8) {
    bf16x8 sv[8];
#pragma unroll
    for (int r = 0; r < 8; r++)
      sv[r] = *(const bf16x8*)(Sp + (size_t)(p0 + pb + r) * Qpad);
#pragma unroll
    for (int r = 0; r < 8; r++)
      for (int j = 0; j < 8; j++)
        acc[j] += __expf(fmaf((float)sv[r][j], id[j], nid[j]));
  }
  float* zp = Zp + ((size_t)n * NSL + blockIdx.y) * Qpad + q;
  *(f32x4*)zp = f32x4{acc[0], acc[1], acc[2], acc[3]};
  *(f32x4*)(zp + 4) = f32x4{acc[4], acc[5], acc[6], acc[7]};
}

// ---- reduce: Z[q] = sum_slab Zp ; invd[q] ; c[q] = -log(Z)-invd ---- grid (13,8)
__global__ __launch_bounds__(256) void reduce_kernel(
    const float* __restrict__ Zp3, const unsigned* __restrict__ dk3,
    float* __restrict__ invd3, float* __restrict__ c3,
    const float* __restrict__ Zp4, const unsigned* __restrict__ dk4,
    float* __restrict__ invd4, float* __restrict__ c4)
{
  int lay = blockIdx.y >> 2, n = blockIdx.y & 3;
  const float* Zp; const unsigned* dk; float *invd, *c; int Qreal, Qpad, NSL;
  if (lay == 0) { Zp = Zp3; dk = dk3; invd = invd3; c = c3; Qreal = 3136; Qpad = 3200; NSL = 98; }
  else          { Zp = Zp4; dk = dk4; invd = invd4; c = c4; Qreal = 784;  Qpad = 896;  NSL = 49; }
  int q = blockIdx.x * 256 + threadIdx.x;
  if (q >= Qreal) return;
  float s0 = 0.f, s1 = 0.f, s2 = 0.f, s3 = 0.f;
  int sl = 0;
  for (; sl + 4 <= NSL; sl += 4) {
    s0 += Zp[((size_t)n * NSL + sl) * Qpad + q];
    s1 += Zp[((size_t)n * NSL + sl + 1) * Qpad + q];
    s2 += Zp[((size_t)n * NSL + sl + 2) * Qpad + q];
    s3 += Zp[((size_t)n * NSL + sl + 3) * Qpad + q];
  }
  for (; sl < NSL; sl++) s0 += Zp[((size_t)n * NSL + sl) * Qpad + q];
  float s = (s0 + s1) + (s2 + s3);
  float mx = funkey(dk[(size_t)n * Qpad + q]);
  float d = 0.5f * (1.f - mx) + EPSV;
  float idv = 1.f / d;
  invd[(size_t)n * Qpad + q] = idv;
  c[(size_t)n * Qpad + q] = -logf(s) - idv;
}

// ---- rowmax: kmax[p] = exp(max_q (S*invd + c)) ; 8 rows/block ---- grid (392,8)
__global__ __launch_bounds__(256) void rowmax_kernel(
    const __bf16* __restrict__ S3, const float* __restrict__ invd3,
    const float* __restrict__ c3, float* __restrict__ km3,
    const __bf16* __restrict__ S4, const float* __restrict__ invd4,
    const float* __restrict__ c4, float* __restrict__ km4)
{
  int lay = blockIdx.y >> 2, n = blockIdx.y & 3;
  const __bf16* S; const float *invd, *cc; float* kmax;
  int Qreal, Qpad, Ppad, NB;
  if (lay == 0) { S = S3; invd = invd3; cc = c3; kmax = km3; Qreal = 3136; Qpad = 3200; Ppad = 3200; NB = 392; }
  else          { S = S4; invd = invd4; cc = c4; kmax = km4; Qreal = 784;  Qpad = 896;  Ppad = 896;  NB = 98; }
  if (blockIdx.x >= (unsigned)NB) return;
  int p0 = blockIdx.x * 8;
  const __bf16* Sp = S + ((size_t)n * Ppad + p0) * Qpad;
  const float* id = invd + (size_t)n * Qpad;
  const float* cp = cc + (size_t)n * Qpad;
  int nq8 = Qreal >> 3;
  float m[8];
#pragma unroll
  for (int r = 0; r < 8; r++) m[r] = -INFINITY;
  for (int i = threadIdx.x; i < nq8; i += 256) {
    f32x4 i0 = *(const f32x4*)(id + (size_t)i * 8);
    f32x4 i1 = *(const f32x4*)(id + (size_t)i * 8 + 4);
    f32x4 c0 = *(const f32x4*)(cp + (size_t)i * 8);
    f32x4 c1 = *(const f32x4*)(cp + (size_t)i * 8 + 4);
#pragma unroll
    for (int r = 0; r < 8; r++) {
      bf16x8 sv = *(const bf16x8*)(Sp + (size_t)r * Qpad + (size_t)i * 8);
      for (int j = 0; j < 4; j++)
        m[r] = fmaxf(m[r], fmaf((float)sv[j], i0[j], c0[j]));
      for (int j = 0; j < 4; j++)
        m[r] = fmaxf(m[r], fmaf((float)sv[j + 4], i1[j], c1[j]));
    }
  }
#pragma unroll
  for (int r = 0; r < 8; r++)
    for (int off = 32; off > 0; off >>= 1)
      m[r] = fmaxf(m[r], __shfl_xor(m[r], off, 64));
  __shared__ float red[4][8];
  int w = threadIdx.x >> 6;
  if ((threadIdx.x & 63) == 0)
    for (int r = 0; r < 8; r++) red[w][r] = m[r];
  __syncthreads();
  if (threadIdx.x < 8) {
    int r = threadIdx.x;
    float mr = fmaxf(fmaxf(red[0][r], red[1][r]), fmaxf(red[2][r], red[3][r]));
    kmax[(size_t)n * Ppad + p0 + r] = __expf(mr);
  }
}

// loss = 0.5 * sum_n -log(mean_p kmax3) + 1.0 * sum_n -log(mean_p kmax4)
__global__ void final_kernel(const float* __restrict__ kmax3, const float* __restrict__ kmax4,
                             float* __restrict__ out)
{
  __shared__ float red[256];
  int tid = threadIdx.x;
  float total = 0.f;
  for (int l = 0; l < 2; l++) {
    const float* km = l ? kmax4 : kmax3;
    int P = l ? 784 : 3136;
    int Ppad = l ? 896 : 3200;
    float wgt = l ? 1.0f : 0.5f;
    for (int n = 0; n < 4; n++) {
      float s = 0.f;
      for (int i = tid; i < P; i += 256) s += km[(size_t)n * Ppad + i];
      red[tid] = s;
      __syncthreads();
      for (int st = 128; st > 0; st >>= 1) {
        if (tid < st) red[tid] += red[tid + st];
        __syncthreads();
      }
      if (tid == 0) total += wgt * (-logf(red[0] / (float)P));
      __syncthreads();
    }
  }
  if (tid == 0) out[0] = total;
}

extern "C" void kernel_launch(void* const* d_in, const int* in_sizes, int n_in,
                              void* d_out, int out_size, void* d_ws, size_t ws_size,
                              hipStream_t stream)
{
  const float* gen3 = (const float*)d_in[0];
  const float* tar3 = (const float*)d_in[1];
  const float* gen4 = (const float*)d_in[2];
  const float* tar4 = (const float*)d_in[3];

  char* ws = (char*)d_ws;
  size_t off = 0;
  auto take = [&](size_t bytes) { char* p = ws + off; off += bytes; return p; };

  // ---- zeroed region (one contiguous memset) ----
  unsigned* divkey3 = (unsigned*)take(51200);   // 4*3200*4
  unsigned* divkey4 = (unsigned*)take(14336);   // 4*896*4
  size_t zero_bytes = off;
  // ---- rest ----
  __bf16* That3 = (__bf16*)take(6553600);       // 4*3200*256*2
  __bf16* Ghat3 = (__bf16*)take(6553600);
  __bf16* That4 = (__bf16*)take(3670016);       // 4*896*512*2
  __bf16* Ghat4 = (__bf16*)take(3670016);
  __bf16* S3    = (__bf16*)take(81920000);      // 4*3200*3200*2
  __bf16* S4    = (__bf16*)take(6422528);       // 4*896*896*2
  float*  Zp3   = (float*) take(5017600);       // 4*98*3200*4
  float*  Zp4   = (float*) take(702464);        // 4*49*896*4
  float* invd3  = (float*)take(51200);
  float* c3     = (float*)take(51200);
  float* kmax3  = (float*)take(51200);
  float* invd4  = (float*)take(14336);
  float* c4     = (float*)take(14336);
  float* kmax4  = (float*)take(14336);

  hipMemsetAsync(divkey3, 0, zero_bytes, stream);

  norm_kernel<<<dim3(1, 100, 8), 256, 0, stream>>>(gen3, tar3, Ghat3, That3,
                                                   gen4, tar4, Ghat4, That4);
  gemm_kernel<<<dim3(25, 25, 8), 256, 0, stream>>>(That3, Ghat3, S3, divkey3,
                                                   That4, Ghat4, S4, divkey4);
  z_kernel<<<dim3(2, 98, 8), 256, 0, stream>>>(S3, divkey3, Zp3,
                                               S4, divkey4, Zp4);
  reduce_kernel<<<dim3(13, 8), 256, 0, stream>>>(Zp3, divkey3, invd3, c3,
                                                 Zp4, divkey4, invd4, c4);
  rowmax_kernel<<<dim3(392, 8), 256, 0, stream>>>(S3, invd3, c3, kmax3,
                                                  S4, invd4, c4, kmax4);
  final_kernel<<<1, 256, 0, stream>>>(kmax3, kmax4, (float*)d_out);
}

// Round 7
// 205.321 us; speedup vs baseline: 2.8961x; 1.0700x over previous
//
#include <hip/hip_runtime.h>
#include <math.h>

typedef __bf16 bf16x8 __attribute__((ext_vector_type(8)));
typedef float f32x4 __attribute__((ext_vector_type(4)));

#define EPSV 1e-5f
#define GLB(p) ((__attribute__((address_space(1))) void*)(p))
#define LDS(p) ((__attribute__((address_space(3))) void*)(p))

__device__ __forceinline__ unsigned fkey(float f) {
  unsigned b = __float_as_uint(f);
  return (b & 0x80000000u) ? ~b : (b | 0x80000000u);
}
__device__ __forceinline__ float funkey(unsigned k) {
  return __uint_as_float((k & 0x80000000u) ? (k & 0x7fffffffu) : ~k);
}

// ---- single-pass norm: block owns p-tile x all C; stats in regs+LDS, then
// apply+store bf16 [N][Ppad][C]. Pad blocks (y>=NWORK) zero the pad rows. ----
// grid (1, 100, 8): z>>2 = layer, z&3 = n.
__global__ __launch_bounds__(256) void norm_kernel(
    const float* __restrict__ g3, const float* __restrict__ t3,
    __bf16* __restrict__ G3, __bf16* __restrict__ T3,
    const float* __restrict__ g4, const float* __restrict__ t4,
    __bf16* __restrict__ G4, __bf16* __restrict__ T4)
{
  int lay = blockIdx.z >> 2, n = blockIdx.z & 3;
  const float *gen, *tar; __bf16 *Gh, *Th; int C, P, Ppad, PT, NWORK, NTOT, NG;
  if (lay == 0) { gen = g3; tar = t3; Gh = G3; Th = T3; C = 256; P = 3136; Ppad = 3200; PT = 32; NWORK = 98; NTOT = 100; NG = 8; }
  else          { gen = g4; tar = t4; Gh = G4; Th = T4; C = 512; P = 784;  Ppad = 896;  PT = 16; NWORK = 49; NTOT = 56;  NG = 16; }
  if (blockIdx.y >= (unsigned)NTOT) return;
  int pl, cg;
  if (lay == 0) { pl = threadIdx.x & 31; cg = threadIdx.x >> 5; }
  else          { pl = threadIdx.x & 15; cg = threadIdx.x >> 4; }
  int c0 = cg * 32;

  if (blockIdx.y >= (unsigned)NWORK) {  // zero pad rows
    int p = P + (blockIdx.y - NWORK) * PT + pl;
    if (p < Ppad) {
      __bf16* tp = Th + ((size_t)n * Ppad + p) * C + c0;
      __bf16* gp = Gh + ((size_t)n * Ppad + p) * C + c0;
      bf16x8 z;
      for (int j = 0; j < 8; j++) z[j] = (__bf16)0.f;
      for (int j = 0; j < 32; j += 8) { *(bf16x8*)(tp + j) = z; *(bf16x8*)(gp + j) = z; }
    }
    return;
  }

  int p = blockIdx.y * PT + pl;
  const float* tb = tar + (size_t)n * C * P + (size_t)c0 * P + p;
  const float* gb = gen + (size_t)n * C * P + (size_t)c0 * P + p;
  float tv[32], gv[32];
  float st = 0.f, sst = 0.f, sg = 0.f, ssg = 0.f;
#pragma unroll
  for (int j = 0; j < 32; j++) {
    tv[j] = tb[(size_t)j * P];
    gv[j] = gb[(size_t)j * P];
  }
#pragma unroll
  for (int j = 0; j < 32; j++) {
    st += tv[j]; sst += tv[j] * tv[j];
    sg += gv[j]; ssg += gv[j] * gv[j];
  }
  __shared__ f32x4 red[16][32];
  red[cg][pl] = f32x4{st, sst, sg, ssg};
  __syncthreads();
  for (int h = NG >> 1; h > 0; h >>= 1) {
    if (cg < h) {
      f32x4 a = red[cg][pl], b = red[cg + h][pl];
      red[cg][pl] = f32x4{a[0] + b[0], a[1] + b[1], a[2] + b[2], a[3] + b[3]};
    }
    __syncthreads();
  }
  f32x4 s = red[0][pl];
  float m = s[0] / (float)C;
  float vt = s[1] - s[0] * s[0] / (float)C;
  float vg = s[3] - 2.f * m * s[2] + (float)C * m * m;
  float it = rsqrtf(fmaxf(vt, 1e-30f));
  float ig = rsqrtf(fmaxf(vg, 1e-30f));
  __bf16* tp = Th + ((size_t)n * Ppad + p) * C + c0;
  __bf16* gp = Gh + ((size_t)n * Ppad + p) * C + c0;
#pragma unroll
  for (int j0 = 0; j0 < 32; j0 += 8) {
    bf16x8 to, go;
    for (int j = 0; j < 8; j++) {
      to[j] = (__bf16)((tv[j0 + j] - m) * it);
      go[j] = (__bf16)((gv[j0 + j] - m) * ig);
    }
    *(bf16x8*)(tp + j0) = to;
    *(bf16x8*)(gp + j0) = go;
  }
}

// ---- GEMM: 128x128 tile, BK=32, single-buffer 2-barrier (m97 structure),
// XOR bank swizzle, band-swizzled 1D grid (2696 blocks), coalesced bf16
// epilogue via LDS bounce (kills store RFO), colmax atomics. ----
__global__ __launch_bounds__(256) void gemm_kernel(
    const __bf16* __restrict__ A3, const __bf16* __restrict__ B3,
    __bf16* __restrict__ So3, unsigned* __restrict__ dk3,
    const __bf16* __restrict__ A4, const __bf16* __restrict__ B4,
    __bf16* __restrict__ So4, unsigned* __restrict__ dk4)
{
  // staging: A at [0,8192), B at [16384,24576) per-stage bytes used;
  // epilogue reuses [0, 36864) as 128 rows x 288 B.
  __shared__ __attribute__((aligned(16))) char smem[36864];

  int id = blockIdx.x;
  const __bf16 *A, *B; __bf16* S; unsigned* dk;
  int C, Ppad, Qpad, Preal, NT, n, t;
  if (id < 2500) {
    n = id / 625; t = id - n * 625;
    A = A3; B = B3; S = So3; dk = dk3; C = 256; Ppad = 3200; Qpad = 3200; Preal = 3136; NT = 25;
  } else {
    id -= 2500;
    n = id / 49; t = id - n * 49;
    A = A4; B = B4; S = So4; dk = dk4; C = 512; Ppad = 896;  Qpad = 896;  Preal = 784;  NT = 7;
  }
  // band swizzle: bands of 8 p-tiles, q fastest within a band
  int bpb = NT * 8;
  int b = t / bpb, r = t - b * bpb;
  int rem = NT - b * 8;
  int h = rem < 8 ? rem : 8;
  int pt = b * 8 + r % h, qt = r / h;
  int p0 = pt * 128, q0 = qt * 128;

  int tid = threadIdx.x;
  int w = tid >> 6, lane = tid & 63;
  int lm = lane & 15, lq = lane >> 4;
  int wrow = (w >> 1) * 64, wcol = (w & 1) * 64;

  // staging: thread tid -> row tid>>2 (and +64), chunk-slot tid&3 (16B);
  // slot s of row r holds global chunk s ^ ((r>>1)&3) (bank swizzle).
  int srow = tid >> 2;
  int scol = ((tid & 3) ^ ((tid >> 3) & 3)) * 8;
  const __bf16* gA = A + ((size_t)n * Ppad + p0 + srow) * C + scol;
  const __bf16* gB = B + ((size_t)n * Qpad + q0 + srow) * C + scol;
  size_t rowoff = (size_t)64 * C;
  char* lA = smem + w * 1024;
  char* lB = smem + 16384 + w * 1024;

  // fragment read: row R + chunk lq -> slot lq ^ ((lm>>1)&3)
  int sl = lq ^ ((lm >> 1) & 3);
  int aoff = (wrow + lm) * 64 + sl * 16;   // + i*1024 per i-tile
  int boff = (wcol + lm) * 64 + sl * 16;

  f32x4 acc[4][4];
  for (int i = 0; i < 4; i++)
    for (int j = 0; j < 4; j++)
      acc[i][j] = f32x4{0.f, 0.f, 0.f, 0.f};

  for (int k0 = 0; k0 < C; k0 += 32) {
    __syncthreads();
    __builtin_amdgcn_global_load_lds(GLB(gA + k0), LDS(lA), 16, 0, 0);
    __builtin_amdgcn_global_load_lds(GLB(gA + rowoff + k0), LDS(lA + 4096), 16, 0, 0);
    __builtin_amdgcn_global_load_lds(GLB(gB + k0), LDS(lB), 16, 0, 0);
    __builtin_amdgcn_global_load_lds(GLB(gB + rowoff + k0), LDS(lB + 4096), 16, 0, 0);
    __syncthreads();
    bf16x8 af[4], bf[4];
    for (int i = 0; i < 4; i++) af[i] = *(const bf16x8*)(smem + aoff + i * 1024);
    for (int j = 0; j < 4; j++) bf[j] = *(const bf16x8*)(smem + 16384 + boff + j * 1024);
    for (int i = 0; i < 4; i++)
      for (int j = 0; j < 4; j++)
        acc[i][j] = __builtin_amdgcn_mfma_f32_16x16x32_bf16(af[i], bf[j], acc[i][j], 0, 0, 0);
  }

  // colmax from registers (D: row = lq*4+ri, col = lm within 16x16 sub-tile)
  float cm[4] = {-INFINITY, -INFINITY, -INFINITY, -INFINITY};
  for (int i = 0; i < 4; i++)
    for (int j = 0; j < 4; j++)
      for (int ri = 0; ri < 4; ri++) {
        int pr = p0 + wrow + i * 16 + lq * 4 + ri;
        if (pr < Preal) cm[j] = fmaxf(cm[j], (float)(__bf16)acc[i][j][ri]);
      }

  // epilogue: bounce through LDS (rows padded to 288 B -> stagger banks),
  // then fully-coalesced bf16x8 row stores.
  __syncthreads();
  for (int i = 0; i < 4; i++) {
    for (int j = 0; j < 4; j++) {
      int row = wrow + i * 16 + lq * 4;
      int col = wcol + j * 16 + lm;
      for (int ri = 0; ri < 4; ri++)
        *(__bf16*)(smem + (row + ri) * 288 + col * 2) = (__bf16)acc[i][j][ri];
    }
  }
  __syncthreads();
  __bf16* Sb = S + (size_t)n * Ppad * Qpad;
  int rr = tid >> 4, cc8 = (tid & 15) * 8;
  for (int r8 = 0; r8 < 8; r8++) {
    int row = r8 * 16 + rr;
    bf16x8 v = *(const bf16x8*)(smem + row * 288 + cc8 * 2);
    *(bf16x8*)(Sb + (size_t)(p0 + row) * Qpad + q0 + cc8) = v;
  }

  for (int j = 0; j < 4; j++) {
    float v = cm[j];
    v = fmaxf(v, __shfl_xor(v, 16, 64));
    v = fmaxf(v, __shfl_xor(v, 32, 64));
    if (lq == 0 && v > -INFINITY) {
      int qc = q0 + wcol + j * 16 + lm;
      atomicMax(&dk[(size_t)n * Qpad + qc], fkey(v));
    }
  }
}

// ---- z partials: block = q-tile(2048) x p-slab(32/16); NO atomics. ----
// grid (2,98,8)
__global__ __launch_bounds__(256) void z_kernel(
    const __bf16* __restrict__ S3, const unsigned* __restrict__ dk3, float* __restrict__ Zp3,
    const __bf16* __restrict__ S4, const unsigned* __restrict__ dk4, float* __restrict__ Zp4)
{
  int lay = blockIdx.z >> 2, n = blockIdx.z & 3;
  const __bf16* S; const unsigned* dk; float* Zp;
  int Ppad, Qreal, Qpad, NSL, SLAB, NX;
  if (lay == 0) { S = S3; dk = dk3; Zp = Zp3; Ppad = 3200; Qreal = 3136; Qpad = 3200; NSL = 98; SLAB = 32; NX = 2; }
  else          { S = S4; dk = dk4; Zp = Zp4; Ppad = 896;  Qreal = 784;  Qpad = 896;  NSL = 49; SLAB = 16; NX = 1; }
  if (blockIdx.x >= (unsigned)NX || blockIdx.y >= (unsigned)NSL) return;
  int q = (blockIdx.x * 256 + threadIdx.x) * 8;
  if (q >= Qreal) return;
  float id[8], nid[8];
  const unsigned* dkp = dk + (size_t)n * Qpad + q;
#pragma unroll
  for (int j = 0; j < 8; j++) {
    float mx = funkey(dkp[j]);
    float d = 0.5f * (1.f - mx) + EPSV;
    id[j] = 1.f / d;
    nid[j] = -id[j];
  }
  int p0 = blockIdx.y * SLAB;
  const __bf16* Sp = S + (size_t)n * Ppad * Qpad + q;
  float acc[8] = {0.f, 0.f, 0.f, 0.f, 0.f, 0.f, 0.f, 0.f};
  for (int pb = 0; pb < SLAB; pb += 8) {
    bf16x8 sv[8];
#pragma unroll
    for (int r = 0; r < 8; r++)
      sv[r] = *(const bf16x8*)(Sp + (size_t)(p0 + pb + r) * Qpad);
#pragma unroll
    for (int r = 0; r < 8; r++)
      for (int j = 0; j < 8; j++)
        acc[j] += __expf(fmaf((float)sv[r][j], id[j], nid[j]));
  }
  float* zp = Zp + ((size_t)n * NSL + blockIdx.y) * Qpad + q;
  *(f32x4*)zp = f32x4{acc[0], acc[1], acc[2], acc[3]};
  *(f32x4*)(zp + 4) = f32x4{acc[4], acc[5], acc[6], acc[7]};
}

// ---- reduce: Z[q] = sum_slab Zp ; invd[q] ; c[q] = -log(Z)-invd ---- grid (13,8)
__global__ __launch_bounds__(256) void reduce_kernel(
    const float* __restrict__ Zp3, const unsigned* __restrict__ dk3,
    float* __restrict__ invd3, float* __restrict__ c3,
    const float* __restrict__ Zp4, const unsigned* __restrict__ dk4,
    float* __restrict__ invd4, float* __restrict__ c4)
{
  int lay = blockIdx.y >> 2, n = blockIdx.y & 3;
  const float* Zp; const unsigned* dk; float *invd, *c; int Qreal, Qpad, NSL;
  if (lay == 0) { Zp = Zp3; dk = dk3; invd = invd3; c = c3; Qreal = 3136; Qpad = 3200; NSL = 98; }
  else          { Zp = Zp4; dk = dk4; invd = invd4; c = c4; Qreal = 784;  Qpad = 896;  NSL = 49; }
  int q = blockIdx.x * 256 + threadIdx.x;
  if (q >= Qreal) return;
  float s0 = 0.f, s1 = 0.f, s2 = 0.f, s3 = 0.f;
  int sl = 0;
  for (; sl + 4 <= NSL; sl += 4) {
    s0 += Zp[((size_t)n * NSL + sl) * Qpad + q];
    s1 += Zp[((size_t)n * NSL + sl + 1) * Qpad + q];
    s2 += Zp[((size_t)n * NSL + sl + 2) * Qpad + q];
    s3 += Zp[((size_t)n * NSL + sl + 3) * Qpad + q];
  }
  for (; sl < NSL; sl++) s0 += Zp[((size_t)n * NSL + sl) * Qpad + q];
  float s = (s0 + s1) + (s2 + s3);
  float mx = funkey(dk[(size_t)n * Qpad + q]);
  float d = 0.5f * (1.f - mx) + EPSV;
  float idv = 1.f / d;
  invd[(size_t)n * Qpad + q] = idv;
  c[(size_t)n * Qpad + q] = -logf(s) - idv;
}

// ---- rowmax: kmax[p] = exp(max_q (S*invd + c)) ; 8 rows/block ---- grid (392,8)
__global__ __launch_bounds__(256) void rowmax_kernel(
    const __bf16* __restrict__ S3, const float* __restrict__ invd3,
    const float* __restrict__ c3, float* __restrict__ km3,
    const __bf16* __restrict__ S4, const float* __restrict__ invd4,
    const float* __restrict__ c4, float* __restrict__ km4)
{
  int lay = blockIdx.y >> 2, n = blockIdx.y & 3;
  const __bf16* S; const float *invd, *cc; float* kmax;
  int Qreal, Qpad, Ppad, NB;
  if (lay == 0) { S = S3; invd = invd3; cc = c3; kmax = km3; Qreal = 3136; Qpad = 3200; Ppad = 3200; NB = 392; }
  else          { S = S4; invd = invd4; cc = c4; kmax = km4; Qreal = 784;  Qpad = 896;  Ppad = 896;  NB = 98; }
  if (blockIdx.x >= (unsigned)NB) return;
  int p0 = blockIdx.x * 8;
  const __bf16* Sp = S + ((size_t)n * Ppad + p0) * Qpad;
  const float* id = invd + (size_t)n * Qpad;
  const float* cp = cc + (size_t)n * Qpad;
  int nq8 = Qreal >> 3;
  float m[8];
#pragma unroll
  for (int r = 0; r < 8; r++) m[r] = -INFINITY;
  for (int i = threadIdx.x; i < nq8; i += 256) {
    f32x4 i0 = *(const f32x4*)(id + (size_t)i * 8);
    f32x4 i1 = *(const f32x4*)(id + (size_t)i * 8 + 4);
    f32x4 c0 = *(const f32x4*)(cp + (size_t)i * 8);
    f32x4 c1 = *(const f32x4*)(cp + (size_t)i * 8 + 4);
#pragma unroll
    for (int r = 0; r < 8; r++) {
      bf16x8 sv = *(const bf16x8*)(Sp + (size_t)r * Qpad + (size_t)i * 8);
      for (int j = 0; j < 4; j++)
        m[r] = fmaxf(m[r], fmaf((float)sv[j], i0[j], c0[j]));
      for (int j = 0; j < 4; j++)
        m[r] = fmaxf(m[r], fmaf((float)sv[j + 4], i1[j], c1[j]));
    }
  }
#pragma unroll
  for (int r = 0; r < 8; r++)
    for (int off = 32; off > 0; off >>= 1)
      m[r] = fmaxf(m[r], __shfl_xor(m[r], off, 64));
  __shared__ float red[4][8];
  int w = threadIdx.x >> 6;
  if ((threadIdx.x & 63) == 0)
    for (int r = 0; r < 8; r++) red[w][r] = m[r];
  __syncthreads();
  if (threadIdx.x < 8) {
    int r = threadIdx.x;
    float mr = fmaxf(fmaxf(red[0][r], red[1][r]), fmaxf(red[2][r], red[3][r]));
    kmax[(size_t)n * Ppad + p0 + r] = __expf(mr);
  }
}

// loss = 0.5 * sum_n -log(mean_p kmax3) + 1.0 * sum_n -log(mean_p kmax4)
__global__ void final_kernel(const float* __restrict__ kmax3, const float* __restrict__ kmax4,
                             float* __restrict__ out)
{
  __shared__ float red[256];
  int tid = threadIdx.x;
  float total = 0.f;
  for (int l = 0; l < 2; l++) {
    const float* km = l ? kmax4 : kmax3;
    int P = l ? 784 : 3136;
    int Ppad = l ? 896 : 3200;
    float wgt = l ? 1.0f : 0.5f;
    for (int n = 0; n < 4; n++) {
      float s = 0.f;
      for (int i = tid; i < P; i += 256) s += km[(size_t)n * Ppad + i];
      red[tid] = s;
      __syncthreads();
      for (int st = 128; st > 0; st >>= 1) {
        if (tid < st) red[tid] += red[tid + st];
        __syncthreads();
      }
      if (tid == 0) total += wgt * (-logf(red[0] / (float)P));
      __syncthreads();
    }
  }
  if (tid == 0) out[0] = total;
}

extern "C" void kernel_launch(void* const* d_in, const int* in_sizes, int n_in,
                              void* d_out, int out_size, void* d_ws, size_t ws_size,
                              hipStream_t stream)
{
  const float* gen3 = (const float*)d_in[0];
  const float* tar3 = (const float*)d_in[1];
  const float* gen4 = (const float*)d_in[2];
  const float* tar4 = (const float*)d_in[3];

  char* ws = (char*)d_ws;
  size_t off = 0;
  auto take = [&](size_t bytes) { char* p = ws + off; off += bytes; return p; };

  // ---- zeroed region (one contiguous memset) ----
  unsigned* divkey3 = (unsigned*)take(51200);   // 4*3200*4
  unsigned* divkey4 = (unsigned*)take(14336);   // 4*896*4
  size_t zero_bytes = off;
  // ---- rest ----
  __bf16* That3 = (__bf16*)take(6553600);       // 4*3200*256*2
  __bf16* Ghat3 = (__bf16*)take(6553600);
  __bf16* That4 = (__bf16*)take(3670016);       // 4*896*512*2
  __bf16* Ghat4 = (__bf16*)take(3670016);
  __bf16* S3    = (__bf16*)take(81920000);      // 4*3200*3200*2
  __bf16* S4    = (__bf16*)take(6422528);       // 4*896*896*2
  float*  Zp3   = (float*) take(5017600);       // 4*98*3200*4
  float*  Zp4   = (float*) take(702464);        // 4*49*896*4
  float* invd3  = (float*)take(51200);
  float* c3     = (float*)take(51200);
  float* kmax3  = (float*)take(51200);
  float* invd4  = (float*)take(14336);
  float* c4     = (float*)take(14336);
  float* kmax4  = (float*)take(14336);

  hipMemsetAsync(divkey3, 0, zero_bytes, stream);

  norm_kernel<<<dim3(1, 100, 8), 256, 0, stream>>>(gen3, tar3, Ghat3, That3,
                                                   gen4, tar4, Ghat4, That4);
  gemm_kernel<<<2696, 256, 0, stream>>>(That3, Ghat3, S3, divkey3,
                                        That4, Ghat4, S4, divkey4);
  z_kernel<<<dim3(2, 98, 8), 256, 0, stream>>>(S3, divkey3, Zp3,
                                               S4, divkey4, Zp4);
  reduce_kernel<<<dim3(13, 8), 256, 0, stream>>>(Zp3, divkey3, invd3, c3,
                                                 Zp4, divkey4, invd4, c4);
  rowmax_kernel<<<dim3(392, 8), 256, 0, stream>>>(S3, invd3, c3, kmax3,
                                                  S4, invd4, c4, kmax4);
  final_kernel<<<1, 256, 0, stream>>>(kmax3, kmax4, (float*)d_out);
}

// Round 8
// 204.911 us; speedup vs baseline: 2.9019x; 1.0020x over previous
//
#include <hip/hip_runtime.h>
#include <math.h>

typedef __bf16 bf16x8 __attribute__((ext_vector_type(8)));
typedef float f32x4 __attribute__((ext_vector_type(4)));

#define EPSV 1e-5f
#define GLB(p) ((__attribute__((address_space(1))) void*)(p))
#define LDS(p) ((__attribute__((address_space(3))) void*)(p))

__device__ __forceinline__ unsigned fkey(float f) {
  unsigned b = __float_as_uint(f);
  return (b & 0x80000000u) ? ~b : (b | 0x80000000u);
}
__device__ __forceinline__ float funkey(unsigned k) {
  return __uint_as_float((k & 0x80000000u) ? (k & 0x7fffffffu) : ~k);
}

// ---- single-pass norm: block owns p-tile x all C; stats in regs+LDS, then
// apply+store bf16 [N][Ppad][C]. Pad blocks (y>=NWORK) zero the pad rows. ----
// grid (1, 100, 8): z>>2 = layer, z&3 = n.
__global__ __launch_bounds__(256) void norm_kernel(
    const float* __restrict__ g3, const float* __restrict__ t3,
    __bf16* __restrict__ G3, __bf16* __restrict__ T3,
    const float* __restrict__ g4, const float* __restrict__ t4,
    __bf16* __restrict__ G4, __bf16* __restrict__ T4)
{
  int lay = blockIdx.z >> 2, n = blockIdx.z & 3;
  const float *gen, *tar; __bf16 *Gh, *Th; int C, P, Ppad, PT, NWORK, NTOT, NG;
  if (lay == 0) { gen = g3; tar = t3; Gh = G3; Th = T3; C = 256; P = 3136; Ppad = 3200; PT = 32; NWORK = 98; NTOT = 100; NG = 8; }
  else          { gen = g4; tar = t4; Gh = G4; Th = T4; C = 512; P = 784;  Ppad = 896;  PT = 16; NWORK = 49; NTOT = 56;  NG = 16; }
  if (blockIdx.y >= (unsigned)NTOT) return;
  int pl, cg;
  if (lay == 0) { pl = threadIdx.x & 31; cg = threadIdx.x >> 5; }
  else          { pl = threadIdx.x & 15; cg = threadIdx.x >> 4; }
  int c0 = cg * 32;

  if (blockIdx.y >= (unsigned)NWORK) {  // zero pad rows
    int p = P + (blockIdx.y - NWORK) * PT + pl;
    if (p < Ppad) {
      __bf16* tp = Th + ((size_t)n * Ppad + p) * C + c0;
      __bf16* gp = Gh + ((size_t)n * Ppad + p) * C + c0;
      bf16x8 z;
      for (int j = 0; j < 8; j++) z[j] = (__bf16)0.f;
      for (int j = 0; j < 32; j += 8) { *(bf16x8*)(tp + j) = z; *(bf16x8*)(gp + j) = z; }
    }
    return;
  }

  int p = blockIdx.y * PT + pl;
  const float* tb = tar + (size_t)n * C * P + (size_t)c0 * P + p;
  const float* gb = gen + (size_t)n * C * P + (size_t)c0 * P + p;
  float tv[32], gv[32];
  float st = 0.f, sst = 0.f, sg = 0.f, ssg = 0.f;
#pragma unroll
  for (int j = 0; j < 32; j++) {
    tv[j] = tb[(size_t)j * P];
    gv[j] = gb[(size_t)j * P];
  }
#pragma unroll
  for (int j = 0; j < 32; j++) {
    st += tv[j]; sst += tv[j] * tv[j];
    sg += gv[j]; ssg += gv[j] * gv[j];
  }
  __shared__ f32x4 red[16][32];
  red[cg][pl] = f32x4{st, sst, sg, ssg};
  __syncthreads();
  for (int h = NG >> 1; h > 0; h >>= 1) {
    if (cg < h) {
      f32x4 a = red[cg][pl], b = red[cg + h][pl];
      red[cg][pl] = f32x4{a[0] + b[0], a[1] + b[1], a[2] + b[2], a[3] + b[3]};
    }
    __syncthreads();
  }
  f32x4 s = red[0][pl];
  float m = s[0] / (float)C;
  float vt = s[1] - s[0] * s[0] / (float)C;
  float vg = s[3] - 2.f * m * s[2] + (float)C * m * m;
  float it = rsqrtf(fmaxf(vt, 1e-30f));
  float ig = rsqrtf(fmaxf(vg, 1e-30f));
  __bf16* tp = Th + ((size_t)n * Ppad + p) * C + c0;
  __bf16* gp = Gh + ((size_t)n * Ppad + p) * C + c0;
#pragma unroll
  for (int j0 = 0; j0 < 32; j0 += 8) {
    bf16x8 to, go;
    for (int j = 0; j < 8; j++) {
      to[j] = (__bf16)((tv[j0 + j] - m) * it);
      go[j] = (__bf16)((gv[j0 + j] - m) * ig);
    }
    *(bf16x8*)(tp + j0) = to;
    *(bf16x8*)(gp + j0) = go;
  }
}

// ---- GEMM: 128x128 tile, BK=64 per barrier-phase (two proven-swizzle BK=32
// buffers -> 8 load_lds in flight, half the barriers), launch_bounds(256,3),
// conflict-free 296-B epilogue bounce, non-temporal S stores. ----
__global__ __launch_bounds__(256, 3) void gemm_kernel(
    const __bf16* __restrict__ A3, const __bf16* __restrict__ B3,
    __bf16* __restrict__ So3, unsigned* __restrict__ dk3,
    const __bf16* __restrict__ A4, const __bf16* __restrict__ B4,
    __bf16* __restrict__ So4, unsigned* __restrict__ dk4)
{
  // staging: A0 [0,8K) A1 [8K,16K) B0 [16K,24K) B1 [24K,32K)
  // epilogue reuse: 128 rows x 296 B = 37888 B
  __shared__ __attribute__((aligned(16))) char smem[37888];

  int id = blockIdx.x;
  const __bf16 *A, *B; __bf16* S; unsigned* dk;
  int C, Ppad, Qpad, Preal, NT, n, t;
  if (id < 2500) {
    n = id / 625; t = id - n * 625;
    A = A3; B = B3; S = So3; dk = dk3; C = 256; Ppad = 3200; Qpad = 3200; Preal = 3136; NT = 25;
  } else {
    id -= 2500;
    n = id / 49; t = id - n * 49;
    A = A4; B = B4; S = So4; dk = dk4; C = 512; Ppad = 896;  Qpad = 896;  Preal = 784;  NT = 7;
  }
  // band swizzle: bands of 8 p-tiles, q fastest within a band
  int bpb = NT * 8;
  int b = t / bpb, r = t - b * bpb;
  int rem = NT - b * 8;
  int h = rem < 8 ? rem : 8;
  int pt = b * 8 + r % h, qt = r / h;
  int p0 = pt * 128, q0 = qt * 128;

  int tid = threadIdx.x;
  int w = tid >> 6, lane = tid & 63;
  int lm = lane & 15, lq = lane >> 4;
  int wrow = (w >> 1) * 64, wcol = (w & 1) * 64;

  // staging: thread tid -> row tid>>2 (and +64), chunk-slot tid&3 (16B);
  // slot s of row r holds global chunk s ^ ((r>>1)&3) (proven 0-conflict).
  int srow = tid >> 2;
  int scol = ((tid & 3) ^ ((tid >> 3) & 3)) * 8;
  const __bf16* gA = A + ((size_t)n * Ppad + p0 + srow) * C + scol;
  const __bf16* gB = B + ((size_t)n * Qpad + q0 + srow) * C + scol;
  size_t rowoff = (size_t)64 * C;

  // fragment read: row R + chunk lq -> slot lq ^ ((lm>>1)&3)
  int sl = lq ^ ((lm >> 1) & 3);
  int aoff = (wrow + lm) * 64 + sl * 16;   // + i*1024 per i-tile
  int boff = (wcol + lm) * 64 + sl * 16;

  f32x4 acc[4][4];
  for (int i = 0; i < 4; i++)
    for (int j = 0; j < 4; j++)
      acc[i][j] = f32x4{0.f, 0.f, 0.f, 0.f};

  for (int k0 = 0; k0 < C; k0 += 64) {
    __syncthreads();
#pragma unroll
    for (int sub = 0; sub < 2; sub++) {
      int kk = k0 + sub * 32;
      char* a = smem + sub * 8192 + w * 1024;
      char* bb = smem + 16384 + sub * 8192 + w * 1024;
      __builtin_amdgcn_global_load_lds(GLB(gA + kk), LDS(a), 16, 0, 0);
      __builtin_amdgcn_global_load_lds(GLB(gA + rowoff + kk), LDS(a + 4096), 16, 0, 0);
      __builtin_amdgcn_global_load_lds(GLB(gB + kk), LDS(bb), 16, 0, 0);
      __builtin_amdgcn_global_load_lds(GLB(gB + rowoff + kk), LDS(bb + 4096), 16, 0, 0);
    }
    __syncthreads();
#pragma unroll
    for (int sub = 0; sub < 2; sub++) {
      const char* ab = smem + sub * 8192;
      const char* bb = smem + 16384 + sub * 8192;
      bf16x8 af[4], bf[4];
      for (int i = 0; i < 4; i++) af[i] = *(const bf16x8*)(ab + aoff + i * 1024);
      for (int j = 0; j < 4; j++) bf[j] = *(const bf16x8*)(bb + boff + j * 1024);
      for (int i = 0; i < 4; i++)
        for (int j = 0; j < 4; j++)
          acc[i][j] = __builtin_amdgcn_mfma_f32_16x16x32_bf16(af[i], bf[j], acc[i][j], 0, 0, 0);
    }
  }

  // colmax from registers (D: row = lq*4+ri, col = lm within 16x16 sub-tile)
  float cm[4] = {-INFINITY, -INFINITY, -INFINITY, -INFINITY};
  for (int i = 0; i < 4; i++)
    for (int j = 0; j < 4; j++)
      for (int ri = 0; ri < 4; ri++) {
        int pr = p0 + wrow + i * 16 + lq * 4 + ri;
        if (pr < Preal) cm[j] = fmaxf(cm[j], (float)(__bf16)acc[i][j][ri]);
      }

  // epilogue: bounce through LDS (296-B pitch: banks = lq*8 + lm/2, conflict-
  // free), then fully-coalesced non-temporal bf16x8 row stores.
  __syncthreads();
  for (int i = 0; i < 4; i++) {
    for (int j = 0; j < 4; j++) {
      int row = wrow + i * 16 + lq * 4;
      int col = wcol + j * 16 + lm;
      for (int ri = 0; ri < 4; ri++)
        *(__bf16*)(smem + (row + ri) * 296 + col * 2) = (__bf16)acc[i][j][ri];
    }
  }
  __syncthreads();
  __bf16* Sb = S + (size_t)n * Ppad * Qpad;
  int rr = tid >> 4, cc8 = (tid & 15) * 8;
  for (int r8 = 0; r8 < 8; r8++) {
    int row = r8 * 16 + rr;
    bf16x8 v = *(const bf16x8*)(smem + row * 296 + cc8 * 2);
    __builtin_nontemporal_store(v, (bf16x8*)(Sb + (size_t)(p0 + row) * Qpad + q0 + cc8));
  }

  for (int j = 0; j < 4; j++) {
    float v = cm[j];
    v = fmaxf(v, __shfl_xor(v, 16, 64));
    v = fmaxf(v, __shfl_xor(v, 32, 64));
    if (lq == 0 && v > -INFINITY) {
      int qc = q0 + wcol + j * 16 + lm;
      atomicMax(&dk[(size_t)n * Qpad + qc], fkey(v));
    }
  }
}

// ---- z partials: block = q-tile(2048) x p-slab(32/16); NO atomics.
// exact 1D grid: 980 blocks ----
__global__ __launch_bounds__(256) void z_kernel(
    const __bf16* __restrict__ S3, const unsigned* __restrict__ dk3, float* __restrict__ Zp3,
    const __bf16* __restrict__ S4, const unsigned* __restrict__ dk4, float* __restrict__ Zp4)
{
  int id = blockIdx.x;
  const __bf16* S; const unsigned* dk; float* Zp;
  int Ppad, Qreal, Qpad, NSL, SLAB, n, qx, sy;
  if (id < 784) {
    n = id / 196; int r = id - n * 196; sy = r >> 1; qx = r & 1;
    S = S3; dk = dk3; Zp = Zp3; Ppad = 3200; Qreal = 3136; Qpad = 3200; NSL = 98; SLAB = 32;
  } else {
    id -= 784;
    n = id / 49; sy = id - n * 49; qx = 0;
    S = S4; dk = dk4; Zp = Zp4; Ppad = 896;  Qreal = 784;  Qpad = 896;  NSL = 49; SLAB = 16;
  }
  int q = (qx * 256 + threadIdx.x) * 8;
  if (q >= Qreal) return;
  float idv[8], nid[8];
  const unsigned* dkp = dk + (size_t)n * Qpad + q;
#pragma unroll
  for (int j = 0; j < 8; j++) {
    float mx = funkey(dkp[j]);
    float d = 0.5f * (1.f - mx) + EPSV;
    idv[j] = 1.f / d;
    nid[j] = -idv[j];
  }
  int p0 = sy * SLAB;
  const __bf16* Sp = S + (size_t)n * Ppad * Qpad + q;
  float acc[8] = {0.f, 0.f, 0.f, 0.f, 0.f, 0.f, 0.f, 0.f};
  for (int pb = 0; pb < SLAB; pb += 8) {
    bf16x8 sv[8];
#pragma unroll
    for (int r = 0; r < 8; r++)
      sv[r] = *(const bf16x8*)(Sp + (size_t)(p0 + pb + r) * Qpad);
#pragma unroll
    for (int r = 0; r < 8; r++)
      for (int j = 0; j < 8; j++)
        acc[j] += __expf(fmaf((float)sv[r][j], idv[j], nid[j]));
  }
  float* zp = Zp + ((size_t)n * NSL + sy) * Qpad + q;
  *(f32x4*)zp = f32x4{acc[0], acc[1], acc[2], acc[3]};
  *(f32x4*)(zp + 4) = f32x4{acc[4], acc[5], acc[6], acc[7]};
}

// ---- reduce: Z[q] = sum_slab Zp ; invd[q] ; c[q] = -log(Z)-invd ---- grid (13,8)
__global__ __launch_bounds__(256) void reduce_kernel(
    const float* __restrict__ Zp3, const unsigned* __restrict__ dk3,
    float* __restrict__ invd3, float* __restrict__ c3,
    const float* __restrict__ Zp4, const unsigned* __restrict__ dk4,
    float* __restrict__ invd4, float* __restrict__ c4)
{
  int lay = blockIdx.y >> 2, n = blockIdx.y & 3;
  const float* Zp; const unsigned* dk; float *invd, *c; int Qreal, Qpad, NSL;
  if (lay == 0) { Zp = Zp3; dk = dk3; invd = invd3; c = c3; Qreal = 3136; Qpad = 3200; NSL = 98; }
  else          { Zp = Zp4; dk = dk4; invd = invd4; c = c4; Qreal = 784;  Qpad = 896;  NSL = 49; }
  int q = blockIdx.x * 256 + threadIdx.x;
  if (q >= Qreal) return;
  float s0 = 0.f, s1 = 0.f, s2 = 0.f, s3 = 0.f;
  int sl = 0;
  for (; sl + 4 <= NSL; sl += 4) {
    s0 += Zp[((size_t)n * NSL + sl) * Qpad + q];
    s1 += Zp[((size_t)n * NSL + sl + 1) * Qpad + q];
    s2 += Zp[((size_t)n * NSL + sl + 2) * Qpad + q];
    s3 += Zp[((size_t)n * NSL + sl + 3) * Qpad + q];
  }
  for (; sl < NSL; sl++) s0 += Zp[((size_t)n * NSL + sl) * Qpad + q];
  float s = (s0 + s1) + (s2 + s3);
  float mx = funkey(dk[(size_t)n * Qpad + q]);
  float d = 0.5f * (1.f - mx) + EPSV;
  float idv = 1.f / d;
  invd[(size_t)n * Qpad + q] = idv;
  c[(size_t)n * Qpad + q] = -logf(s) - idv;
}

// ---- rowmax: kmax[p] = exp(max_q (S*invd + c)) ; 8 rows/block;
// exact 1D grid: 1960 blocks ----
__global__ __launch_bounds__(256) void rowmax_kernel(
    const __bf16* __restrict__ S3, const float* __restrict__ invd3,
    const float* __restrict__ c3, float* __restrict__ km3,
    const __bf16* __restrict__ S4, const float* __restrict__ invd4,
    const float* __restrict__ c4, float* __restrict__ km4)
{
  int id = blockIdx.x;
  const __bf16* S; const float *invd, *cc; float* kmax;
  int Qreal, Qpad, Ppad, n, blk;
  if (id < 1568) {
    n = id / 392; blk = id - n * 392;
    S = S3; invd = invd3; cc = c3; kmax = km3; Qreal = 3136; Qpad = 3200; Ppad = 3200;
  } else {
    id -= 1568;
    n = id / 98; blk = id - n * 98;
    S = S4; invd = invd4; cc = c4; kmax = km4; Qreal = 784;  Qpad = 896;  Ppad = 896;
  }
  int p0 = blk * 8;
  const __bf16* Sp = S + ((size_t)n * Ppad + p0) * Qpad;
  const float* idp = invd + (size_t)n * Qpad;
  const float* cp = cc + (size_t)n * Qpad;
  int nq8 = Qreal >> 3;
  float m[8];
#pragma unroll
  for (int r = 0; r < 8; r++) m[r] = -INFINITY;
  for (int i = threadIdx.x; i < nq8; i += 256) {
    f32x4 i0 = *(const f32x4*)(idp + (size_t)i * 8);
    f32x4 i1 = *(const f32x4*)(idp + (size_t)i * 8 + 4);
    f32x4 c0 = *(const f32x4*)(cp + (size_t)i * 8);
    f32x4 c1 = *(const f32x4*)(cp + (size_t)i * 8 + 4);
#pragma unroll
    for (int r = 0; r < 8; r++) {
      bf16x8 sv = *(const bf16x8*)(Sp + (size_t)r * Qpad + (size_t)i * 8);
      for (int j = 0; j < 4; j++)
        m[r] = fmaxf(m[r], fmaf((float)sv[j], i0[j], c0[j]));
      for (int j = 0; j < 4; j++)
        m[r] = fmaxf(m[r], fmaf((float)sv[j + 4], i1[j], c1[j]));
    }
  }
#pragma unroll
  for (int r = 0; r < 8; r++)
    for (int off = 32; off > 0; off >>= 1)
      m[r] = fmaxf(m[r], __shfl_xor(m[r], off, 64));
  __shared__ float red[4][8];
  int w = threadIdx.x >> 6;
  if ((threadIdx.x & 63) == 0)
    for (int r = 0; r < 8; r++) red[w][r] = m[r];
  __syncthreads();
  if (threadIdx.x < 8) {
    int r = threadIdx.x;
    float mr = fmaxf(fmaxf(red[0][r], red[1][r]), fmaxf(red[2][r], red[3][r]));
    kmax[(size_t)n * Ppad + p0 + r] = __expf(mr);
  }
}

// loss = 0.5 * sum_n -log(mean_p kmax3) + 1.0 * sum_n -log(mean_p kmax4)
__global__ void final_kernel(const float* __restrict__ kmax3, const float* __restrict__ kmax4,
                             float* __restrict__ out)
{
  __shared__ float red[256];
  int tid = threadIdx.x;
  float total = 0.f;
  for (int l = 0; l < 2; l++) {
    const float* km = l ? kmax4 : kmax3;
    int P = l ? 784 : 3136;
    int Ppad = l ? 896 : 3200;
    float wgt = l ? 1.0f : 0.5f;
    for (int n = 0; n < 4; n++) {
      float s = 0.f;
      for (int i = tid; i < P; i += 256) s += km[(size_t)n * Ppad + i];
      red[tid] = s;
      __syncthreads();
      for (int st = 128; st > 0; st >>= 1) {
        if (tid < st) red[tid] += red[tid + st];
        __syncthreads();
      }
      if (tid == 0) total += wgt * (-logf(red[0] / (float)P));
      __syncthreads();
    }
  }
  if (tid == 0) out[0] = total;
}

extern "C" void kernel_launch(void* const* d_in, const int* in_sizes, int n_in,
                              void* d_out, int out_size, void* d_ws, size_t ws_size,
                              hipStream_t stream)
{
  const float* gen3 = (const float*)d_in[0];
  const float* tar3 = (const float*)d_in[1];
  const float* gen4 = (const float*)d_in[2];
  const float* tar4 = (const float*)d_in[3];

  char* ws = (char*)d_ws;
  size_t off = 0;
  auto take = [&](size_t bytes) { char* p = ws + off; off += bytes; return p; };

  // ---- zeroed region (one contiguous memset) ----
  unsigned* divkey3 = (unsigned*)take(51200);   // 4*3200*4
  unsigned* divkey4 = (unsigned*)take(14336);   // 4*896*4
  size_t zero_bytes = off;
  // ---- rest ----
  __bf16* That3 = (__bf16*)take(6553600);       // 4*3200*256*2
  __bf16* Ghat3 = (__bf16*)take(6553600);
  __bf16* That4 = (__bf16*)take(3670016);       // 4*896*512*2
  __bf16* Ghat4 = (__bf16*)take(3670016);
  __bf16* S3    = (__bf16*)take(81920000);      // 4*3200*3200*2
  __bf16* S4    = (__bf16*)take(6422528);       // 4*896*896*2
  float*  Zp3   = (float*) take(5017600);       // 4*98*3200*4
  float*  Zp4   = (float*) take(702464);        // 4*49*896*4
  float* invd3  = (float*)take(51200);
  float* c3     = (float*)take(51200);
  float* kmax3  = (float*)take(51200);
  float* invd4  = (float*)take(14336);
  float* c4     = (float*)take(14336);
  float* kmax4  = (float*)take(14336);

  hipMemsetAsync(divkey3, 0, zero_bytes, stream);

  norm_kernel<<<dim3(1, 100, 8), 256, 0, stream>>>(gen3, tar3, Ghat3, That3,
                                                   gen4, tar4, Ghat4, That4);
  gemm_kernel<<<2696, 256, 0, stream>>>(That3, Ghat3, S3, divkey3,
                                        That4, Ghat4, S4, divkey4);
  z_kernel<<<980, 256, 0, stream>>>(S3, divkey3, Zp3,
                                    S4, divkey4, Zp4);
  reduce_kernel<<<dim3(13, 8), 256, 0, stream>>>(Zp3, divkey3, invd3, c3,
                                                 Zp4, divkey4, invd4, c4);
  rowmax_kernel<<<1960, 256, 0, stream>>>(S3, invd3, c3, kmax3,
                                          S4, invd4, c4, kmax4);
  final_kernel<<<1, 256, 0, stream>>>(kmax3, kmax4, (float*)d_out);
}